// Round 7
// baseline (2882.748 us; speedup 1.0000x reference)
//
#include <hip/hip_runtime.h>
#include <cstdint>
#include <cstddef>

// ---------------------------------------------------------------------------
// Pointer-network decoder: B=128 batches decode T=32 steps over N=512 nodes.
// One block per batch (grid 128, 1024 threads, 16 waves).
// Round 9: static wave-specialization. gates(t+1)'s Whh·h half only needs
// h(t+1) (ready after P2(t)), so waves 8-15 compute it DURING P3/P4/P5/P6
// (sections S3/S4), publishing pgh0/pgh1 for the next step's S2 combine.
// The critical path per step shrinks to: S1 (Wih·x split over all 16 waves)
// -> S2 (cell) -> S3 (dt full-dot, 2 waves) -> S4 (scores+argmax, 8 waves)
// -> S5 (distributed argmax finale + softmax + select). 5 barriers/step
// (was 7), no single-thread serial sections on the path (outputs emitted by
// thread 0 under S1's GEMV; argmax finale replicated across 512 threads).
// All sync is whole-block __syncthreads at top level -- no flags, no races.
// Every accumulation chain is bitwise-identical to round 4 (absmax 0.0):
//   gates: ((a0x+a0h)+(a1x+a1h))+bsum ; dt: ((p0+p1)+p2)+p3 ;
//   scores: (a0+a1)+(b0+b1) with the same even/odd-k assignment.
// VGPR envelope (rounds 1-5): wg=1024 -> 64 regs; this design needs ~48
// (no register staging). Tell for trouble: WRITE_SIZE >> 1 MB = spill.
// Sampling reproduces jax.random.categorical bit-exactly (threefry2x32).
// ---------------------------------------------------------------------------

constexpr int B = 128, N = 512, H = 128, T = 32;
constexpr int G4 = 4 * H;  // 512
constexpr float TINYF = 1.17549435e-38f;  // np.finfo(float32).tiny

// ---- JAX threefry2x32 block cipher (20 rounds) ----------------------------
__host__ __device__ inline uint32_t rotl32(uint32_t v, int d) {
  return (v << d) | (v >> (32 - d));
}

__host__ __device__ inline void tf2x32(uint32_t k0, uint32_t k1,
                                       uint32_t x0, uint32_t x1,
                                       uint32_t& o0, uint32_t& o1) {
  uint32_t ks2 = k0 ^ k1 ^ 0x1BD11BDAu;
  x0 += k0; x1 += k1;
#define TF_R(r) x0 += x1; x1 = rotl32(x1, (r)); x1 ^= x0;
  TF_R(13) TF_R(15) TF_R(26) TF_R(6)
  x0 += k1; x1 += ks2 + 1u;
  TF_R(17) TF_R(29) TF_R(16) TF_R(24)
  x0 += ks2; x1 += k0 + 2u;
  TF_R(13) TF_R(15) TF_R(26) TF_R(6)
  x0 += k0; x1 += k1 + 3u;
  TF_R(17) TF_R(29) TF_R(16) TF_R(24)
  x0 += k1; x1 += ks2 + 4u;
  TF_R(13) TF_R(15) TF_R(26) TF_R(6)
  x0 += ks2; x1 += k0 + 5u;
#undef TF_R
  o0 = x0; o1 = x1;
}

struct KeyArgs { uint32_t k[2 * T]; };  // per-step subkeys, 256 B by value

// Host-side key chain (partitionable split): key0 = (0,42);
// new_key = E_key(0,0), sub = E_key(0,1).
static KeyArgs make_subkeys() {
  KeyArgs ka;
  uint32_t k0 = 0u, k1 = 42u;
  for (int t = 0; t < T; ++t) {
    uint32_t n0, n1, s0, s1;
    tf2x32(k0, k1, 0u, 0u, n0, n1);
    tf2x32(k0, k1, 0u, 1u, s0, s1);
    ka.k[2 * t] = s0; ka.k[2 * t + 1] = s1;
    k0 = n0; k1 = n1;
  }
  return ka;
}

// 32-bit draw i (of 65536) for this step's subkey: w0^w1 of E_sub(0, i)
__device__ inline uint32_t gumbel_bits(uint32_t sk0, uint32_t sk1, int i) {
  uint32_t o0, o1;
  tf2x32(sk0, sk1, 0u, (uint32_t)i, o0, o1);
  return o0 ^ o1;
}

// fast tanh for the score hot loop; abs err ~2e-7 (clamp avoids inf/inf NaN)
__device__ inline float fast_tanh(float x) {
  float cx = fminf(9.0f, fmaxf(-9.0f, x));
  float t = __expf(2.0f * cx);
  return (t - 1.0f) * __builtin_amdgcn_rcpf(t + 1.0f);
}

// ---- setup kernel 1: transpose weights for coalesced access ---------------
__global__ void k_transpose(const float* __restrict__ Wih, const float* __restrict__ Whh,
                            const float* __restrict__ W2, const float* __restrict__ W1,
                            float* __restrict__ WihT, float* __restrict__ WhhT,
                            float* __restrict__ W2T, float* __restrict__ W1T) {
  int i = blockIdx.x * blockDim.x + threadIdx.x;
  if (i < H * G4) {
    int h = i >> 9, j = i & (G4 - 1);
    WihT[i] = Wih[j * H + h];
  } else if (i < 2 * H * G4) {
    int q = i - H * G4; int h = q >> 9, j = q & (G4 - 1);
    WhhT[q] = Whh[j * H + h];
  } else if (i < 2 * H * G4 + H * H) {
    int q = i - 2 * H * G4; int h = q >> 7, k = q & (H - 1);
    W2T[q] = W2[k * H + h];
  } else if (i < 2 * H * G4 + 2 * H * H) {
    int q = i - 2 * H * G4 - H * H; int h = q >> 7, k = q & (H - 1);
    W1T[q] = W1[k * H + h];
  }
}

// ---- setup kernel 2: encT2[b,k,n] = sum_h enc[b,n,h] * W1[k,h] ------------
// (k-major output for the decode score SGEMV). 16 enc rows staged in LDS;
// 256 threads = 128 k x 2 n-groups; per-thread 8 consecutive n -> 2x float4.
__global__ __launch_bounds__(256) void k_enc_trans(const float* __restrict__ enc,
                                                   const float* __restrict__ W1T,
                                                   float* __restrict__ encT2) {
  __shared__ __align__(16) float es[16 * 128];  // 8 KB
  int blk = blockIdx.x;
  int b = blk >> 5;               // 32 blocks per batch
  int n0 = (blk & 31) << 4;       // 16 rows
  const float* src = enc + ((size_t)b * N + n0) * H;
  for (int i = threadIdx.x; i < 16 * 128; i += 256) es[i] = src[i];
  __syncthreads();
  int k = threadIdx.x & 127, ng = threadIdx.x >> 7;
  float acc[8] = {0.f, 0.f, 0.f, 0.f, 0.f, 0.f, 0.f, 0.f};
  for (int h = 0; h < H; h += 4) {
    float w0 = W1T[(h + 0) * H + k];   // coalesced (lanes = consecutive k)
    float w1 = W1T[(h + 1) * H + k];
    float w2 = W1T[(h + 2) * H + k];
    float w3 = W1T[(h + 3) * H + k];
#pragma unroll
    for (int j = 0; j < 8; ++j) {
      const float4 e = *(const float4*)&es[(ng * 8 + j) * 128 + h];  // broadcast
      acc[j] += w0 * e.x + w1 * e.y + w2 * e.z + w3 * e.w;
    }
  }
  float* dst = encT2 + (size_t)b * H * N + (size_t)k * N + n0 + ng * 8;
  ((float4*)dst)[0] = make_float4(acc[0], acc[1], acc[2], acc[3]);
  ((float4*)dst)[1] = make_float4(acc[4], acc[5], acc[6], acc[7]);
}

// ---- main fused decoder: 1 batch/block, 1024 threads, wave-specialized ----
// Dynamic LDS (128 KB): e_lds[64][512] = encT2[b][0..63][:] (P4's a-half).
// Waves 0-7 (tid<512): main chain. Waves 8-15 (tid>=512): next-step Whh GEMV.
__global__ __launch_bounds__(1024) void k_decode(
    const float* __restrict__ enc, const float* __restrict__ encT2,
    const float* __restrict__ WihT, const float* __restrict__ WhhT,
    const float* __restrict__ W2T,
    const float* __restrict__ bih, const float* __restrict__ bhh,
    const float* __restrict__ v,
    KeyArgs keys, float* __restrict__ out) {
  __shared__ __align__(16) float xs[H];      // dec_input
  __shared__ __align__(16) float hs[H];      // hx
  __shared__ __align__(16) float cs[H];      // cx
  __shared__ __align__(16) float dt[H];      // dec_trans = hx @ W2^T
  __shared__ __align__(16) float vv[H];
  __shared__ __align__(16) float bsum[G4];   // b_ih + b_hh
  __shared__ __align__(16) float pgx[2][G4]; // Wih·x partials (h-halves)
  __shared__ __align__(16) float pgh0[G4];   // Whh·h partial, h 0..63
  __shared__ __align__(16) float pgh1[G4];   // Whh·h partial, h 64..127
  __shared__ float pdt[4][H];                // init-mean partials (prologue only)
  __shared__ float sc[N];                    // masked scores
  __shared__ float wr_z[8], wr_m[8], wr_s[8];
  __shared__ int wr_i[8];

  extern __shared__ __align__(16) float e_lds[];  // 64*512 floats = 128 KB

  const int tid = threadIdx.x;
  const int b = blockIdx.x;
  const int lane = tid & 63;
  const int wave = tid >> 6;   // 0..15 (wr arrays only used by waves 0..7)

  // ---- LDS-stage encT2[b][0..63][:] (128 KB), coalesced float4 ------------
  {
    const float4* src4 = (const float4*)(encT2 + (size_t)b * (H * N));
    float4* dst4 = (float4*)e_lds;
#pragma unroll
    for (int i = 0; i < 8; ++i) dst4[tid + i * 1024] = src4[tid + i * 1024];
  }

  // ---- init: dec_input = mean_n enc[b,n,:]; h = c = 0; pgh = 0 ------------
  if (tid < 512) {
    int h = tid & 127, part = tid >> 7;
    float s = 0.f;
    const float* p = enc + ((size_t)b * N + part * 128) * H + h;
#pragma unroll 8
    for (int n = 0; n < 128; ++n) s += p[(size_t)n * H];  // coalesced across h
    pdt[part][h] = s;
    bsum[tid] = bih[tid] + bhh[tid];
    pgh0[tid] = 0.f;   // Whh @ h(-1) = Whh @ 0
    pgh1[tid] = 0.f;
  }
  if (tid < 128) { hs[tid] = 0.f; cs[tid] = 0.f; vv[tid] = v[tid]; }
  __syncthreads();
  if (tid < 128)
    xs[tid] = (pdt[0][tid] + pdt[1][tid] + pdt[2][tid] + pdt[3][tid]) * (1.0f / N);
  bool masked = false;     // thread tid (<512) owns node tid
  int sidx_r = 0;          // previous step's sampled idx (per-thread, uniform)
  float smax_r = 0.f;      // previous step's score max
  __syncthreads();

  for (int t = 0; t < T; ++t) {
    // === S1: Wih·x split over ALL 16 waves (thread j=tid&511, half hi) =====
    // hi=0 chain == round 4's a0x (h 0..63 ascending, 4-grouped); hi=1 == a1x.
    // Thread 0 additionally emits the previous step's outputs (hidden).
    {
      if (tid == 0 && t > 0) {
        float sum = wr_s[0] + wr_s[1] + wr_s[2] + wr_s[3]
                  + wr_s[4] + wr_s[5] + wr_s[6] + wr_s[7];
        float p = expf(sc[sidx_r] - smax_r) / sum;
        out[(size_t)b * T + (t - 1)] = (float)sidx_r;
        out[(size_t)B * T + (size_t)b * T + (t - 1)] = logf(p + 1e-9f);
      }
      const int j = tid & 511, hi = tid >> 9;
      const float* wi = WihT + (size_t)(hi * 64) * G4 + j;
      const float* xp = &xs[hi * 64];
      float a = 0.f;
#pragma unroll 8
      for (int h = 0; h < 64; h += 4) {
        const float4 xv = *(const float4*)&xp[h];
        a += wi[(size_t)(h + 0) * G4] * xv.x;
        a += wi[(size_t)(h + 1) * G4] * xv.y;
        a += wi[(size_t)(h + 2) * G4] * xv.z;
        a += wi[(size_t)(h + 3) * G4] * xv.w;
      }
      pgx[hi][j] = a;
    }
    __syncthreads();
    // === S2: cell update (torch gate order i,f,g,o) ========================
    // gate = ((a0x+a0h)+(a1x+a1h)) + bsum  -- bitwise == round 4.
    if (tid < 128) {
      float gi = ((pgx[0][tid] + pgh0[tid]) + (pgx[1][tid] + pgh1[tid])) + bsum[tid];
      float gf = ((pgx[0][H + tid] + pgh0[H + tid]) + (pgx[1][H + tid] + pgh1[H + tid])) + bsum[H + tid];
      float gg = ((pgx[0][2 * H + tid] + pgh0[2 * H + tid]) + (pgx[1][2 * H + tid] + pgh1[2 * H + tid])) + bsum[2 * H + tid];
      float go = ((pgx[0][3 * H + tid] + pgh0[3 * H + tid]) + (pgx[1][3 * H + tid] + pgh1[3 * H + tid])) + bsum[3 * H + tid];
      gi = 1.0f / (1.0f + expf(-gi));
      gf = 1.0f / (1.0f + expf(-gf));
      gg = tanhf(gg);
      go = 1.0f / (1.0f + expf(-go));
      float c = gf * cs[tid] + gi * gg;
      cs[tid] = c;
      hs[tid] = go * tanhf(c);
    }
    __syncthreads();
    // === S3: [waves 0-1] dt full-dot; [waves 8-15] Whh·h, h 0..63 ==========
    float a0h = 0.f, a1h = 0.f;  // W-group accumulators (persist into S4)
    if (tid < 128) {
      // dt[k] = ((p0+p1)+p2)+p3, each p = 32-h ascending 4-grouped chain
      // -- bitwise == round 4's pdt[0..3] + left-assoc combine.
      const float* w2 = W2T + tid;
      float p0 = 0.f, p1 = 0.f, p2 = 0.f, p3 = 0.f;
#pragma unroll 8
      for (int h = 0; h < 32; h += 4) {
        const float4 hv = *(const float4*)&hs[h];
        p0 += w2[(size_t)(h + 0) * H] * hv.x;
        p0 += w2[(size_t)(h + 1) * H] * hv.y;
        p0 += w2[(size_t)(h + 2) * H] * hv.z;
        p0 += w2[(size_t)(h + 3) * H] * hv.w;
      }
#pragma unroll 8
      for (int h = 32; h < 64; h += 4) {
        const float4 hv = *(const float4*)&hs[h];
        p1 += w2[(size_t)(h + 0) * H] * hv.x;
        p1 += w2[(size_t)(h + 1) * H] * hv.y;
        p1 += w2[(size_t)(h + 2) * H] * hv.z;
        p1 += w2[(size_t)(h + 3) * H] * hv.w;
      }
#pragma unroll 8
      for (int h = 64; h < 96; h += 4) {
        const float4 hv = *(const float4*)&hs[h];
        p2 += w2[(size_t)(h + 0) * H] * hv.x;
        p2 += w2[(size_t)(h + 1) * H] * hv.y;
        p2 += w2[(size_t)(h + 2) * H] * hv.z;
        p2 += w2[(size_t)(h + 3) * H] * hv.w;
      }
#pragma unroll 8
      for (int h = 96; h < 128; h += 4) {
        const float4 hv = *(const float4*)&hs[h];
        p3 += w2[(size_t)(h + 0) * H] * hv.x;
        p3 += w2[(size_t)(h + 1) * H] * hv.y;
        p3 += w2[(size_t)(h + 2) * H] * hv.z;
        p3 += w2[(size_t)(h + 3) * H] * hv.w;
      }
      dt[tid] = ((p0 + p1) + p2) + p3;
    } else if (tid >= 512) {
      // a0h: h 0..63 ascending 4-grouped -- bitwise == round 4's a0h chain.
      const int j = tid - 512;
      const float* wh = WhhT + j;
#pragma unroll 8
      for (int h = 0; h < 64; h += 4) {
        const float4 hv = *(const float4*)&hs[h];
        a0h += wh[(size_t)(h + 0) * G4] * hv.x;
        a0h += wh[(size_t)(h + 1) * G4] * hv.y;
        a0h += wh[(size_t)(h + 2) * G4] * hv.z;
        a0h += wh[(size_t)(h + 3) * G4] * hv.w;
      }
    }
    __syncthreads();
    // === S4: [waves 0-7] scores+gumbel+wave argmax; [8-15] Whh h 64..127 ===
    float s = 0.f;  // masked score (used again in S5)
    if (tid < 512) {
      // a-half k 0..63 from LDS (same bits round 4 held in er regs);
      // b-half k 64..127 streamed from L2. Even/odd-k accumulator split and
      // final (a0+a1)+(b0+b1) bitwise == round 4.
      float a0 = 0.f, a1 = 0.f;
      const float* el = e_lds + tid;
#pragma unroll
      for (int k4 = 0; k4 < 64; k4 += 4) {
        const float e0 = el[(k4 + 0) * 512];
        const float e1 = el[(k4 + 1) * 512];
        const float e2 = el[(k4 + 2) * 512];
        const float e3 = el[(k4 + 3) * 512];
        const float4 dv = *(const float4*)&dt[k4];
        const float4 vw = *(const float4*)&vv[k4];
        a0 += vw.x * fast_tanh(e0 + dv.x);
        a1 += vw.y * fast_tanh(e1 + dv.y);
        a0 += vw.z * fast_tanh(e2 + dv.z);
        a1 += vw.w * fast_tanh(e3 + dv.w);
      }
      float b0 = 0.f, b1 = 0.f;
      const float* eg = encT2 + (size_t)b * (H * N) + (size_t)64 * N + tid;
#pragma unroll 4
      for (int k4 = 0; k4 < 64; k4 += 4) {
        const float e0 = eg[(size_t)(k4 + 0) * N];
        const float e1 = eg[(size_t)(k4 + 1) * N];
        const float e2 = eg[(size_t)(k4 + 2) * N];
        const float e3 = eg[(size_t)(k4 + 3) * N];
        const float4 dv = *(const float4*)&dt[64 + k4];
        const float4 vw = *(const float4*)&vv[64 + k4];
        b0 += vw.x * fast_tanh(e0 + dv.x);
        b1 += vw.y * fast_tanh(e1 + dv.y);
        b0 += vw.z * fast_tanh(e2 + dv.z);
        b1 += vw.w * fast_tanh(e3 + dv.w);
      }
      const float s_score = (a0 + a1) + (b0 + b1);
      s = masked ? -INFINITY : s_score;
      sc[tid] = s;
      uint32_t bits = gumbel_bits(keys.k[2 * t], keys.k[2 * t + 1], b * N + tid);
      // XLA uniform(minval=tiny, maxval=1): bits->[1,2)->-1, +tiny, max
      float f = __uint_as_float((bits >> 9) | 0x3f800000u) - 1.0f;
      float u = fmaxf(TINYF, f + TINYF);
      float g = -logf(-logf(u));  // accurate logf (hw log2 too sloppy near u~1)
      float z = s + g;
      int zi = tid;
      float m = s;
#pragma unroll
      for (int d = 32; d >= 1; d >>= 1) {
        float oz = __shfl_xor(z, d);
        int oi = __shfl_xor(zi, d);
        float om = __shfl_xor(m, d);
        if (oz > z || (oz == z && oi < zi)) { z = oz; zi = oi; }  // first-idx ties
        m = fmaxf(m, om);
      }
      if (lane == 0) { wr_z[wave] = z; wr_i[wave] = zi; wr_m[wave] = m; }
    } else {
      // a1h: h 64..127 ascending 4-grouped -- bitwise == round 4's a1h.
      const int j = tid - 512;
      const float* wh = WhhT + j;
#pragma unroll 8
      for (int h = 64; h < 128; h += 4) {
        const float4 hv = *(const float4*)&hs[h];
        a1h += wh[(size_t)(h + 0) * G4] * hv.x;
        a1h += wh[(size_t)(h + 1) * G4] * hv.y;
        a1h += wh[(size_t)(h + 2) * G4] * hv.z;
        a1h += wh[(size_t)(h + 3) * G4] * hv.w;
      }
      pgh0[j] = a0h;
      pgh1[j] = a1h;
    }
    __syncthreads();
    // === S5: distributed argmax finale + softmax partials + select =========
    if (tid < 512) {
      // every thread replicates the 8-way compare chain (== round 4's P5b)
      float bz = wr_z[0]; int bi = wr_i[0]; float bm = wr_m[0];
#pragma unroll
      for (int w = 1; w < 8; ++w) {
        if (wr_z[w] > bz || (wr_z[w] == bz && wr_i[w] < bi)) { bz = wr_z[w]; bi = wr_i[w]; }
        bm = fmaxf(bm, wr_m[w]);
      }
      sidx_r = bi; smax_r = bm;
      float xnew = 0.f;
      if (tid < 128) xnew = enc[((size_t)b * N + bi) * H + tid];  // issue early
      float e = expf(s - bm);  // masked: exp(-inf) = 0
#pragma unroll
      for (int d = 32; d >= 1; d >>= 1) e += __shfl_xor(e, d);
      if (lane == 0) wr_s[wave] = e;
      if (tid == bi) masked = true;
      if (tid < 128) xs[tid] = xnew;
    }
    __syncthreads();
  }
  // epilogue: outputs for the final step
  if (tid == 0) {
    float sum = wr_s[0] + wr_s[1] + wr_s[2] + wr_s[3]
              + wr_s[4] + wr_s[5] + wr_s[6] + wr_s[7];
    float p = expf(sc[sidx_r] - smax_r) / sum;
    out[(size_t)b * T + (T - 1)] = (float)sidx_r;
    out[(size_t)B * T + (size_t)b * T + (T - 1)] = logf(p + 1e-9f);
  }
}

// ---------------------------------------------------------------------------
extern "C" void kernel_launch(void* const* d_in, const int* in_sizes, int n_in,
                              void* d_out, int out_size, void* d_ws, size_t ws_size,
                              hipStream_t stream) {
  (void)in_sizes; (void)n_in; (void)out_size; (void)ws_size;
  const float* enc = (const float*)d_in[0];
  const float* Wih = (const float*)d_in[1];
  const float* Whh = (const float*)d_in[2];
  const float* bih = (const float*)d_in[3];
  const float* bhh = (const float*)d_in[4];
  const float* W1  = (const float*)d_in[5];
  const float* W2  = (const float*)d_in[6];
  const float* v   = (const float*)d_in[7];
  float* out = (float*)d_out;
  float* ws = (float*)d_ws;

  // ws layout (floats): WihT 65536 | WhhT 65536 | W2T 16384 | W1T 16384 | encT2 8388608
  float* WihT  = ws;
  float* WhhT  = ws + 65536;
  float* W2T   = ws + 131072;
  float* W1T   = ws + 147456;
  float* encT2 = ws + 163840;   // [b][k][n], ~33.5 MB

  KeyArgs keys = make_subkeys();  // pure host arithmetic: capture-safe

  // allow 128KB dynamic LDS for k_decode (host-side attr; capture-safe)
  static bool lds_attr_set = false;
  if (!lds_attr_set) {
    (void)hipFuncSetAttribute(reinterpret_cast<const void*>(k_decode),
                              hipFuncAttributeMaxDynamicSharedMemorySize, 131072);
    lds_attr_set = true;
  }

  k_transpose<<<640, 256, 0, stream>>>(Wih, Whh, W2, W1, WihT, WhhT, W2T, W1T);
  k_enc_trans<<<B * N / 16, 256, 0, stream>>>(enc, W1T, encT2);
  k_decode<<<B, 1024, 131072, stream>>>(enc, encT2, WihT, WhhT, W2T,
                                        bih, bhh, v, keys, out);
}

// Round 8
// 2368.520 us; speedup vs baseline: 1.2171x; 1.2171x over previous
//
#include <hip/hip_runtime.h>
#include <cstdint>
#include <cstddef>

// ---------------------------------------------------------------------------
// Pointer-network decoder: B=128 batches decode T=32 steps over N=512 nodes.
// One block per batch (grid 128, 512 threads, 8 waves) -- the PROVEN spill-
// free envelope (R4: wg=512 + waves_per_eu(2,2) -> 128 VGPRs honored).
// Round 10: within-thread overlap of the next step's Whh.h GEMV under the
// score phase. R7 proved the concept's timing is legal (h(t+1) is final
// after the cell update) but spilled at the wg=1024/64-reg cap. Here each
// thread (node n = tid, gate j = tid) fuses its Whh row-GEMV into the
// trans-pipe-heavy score loop (complementary pipes, one straight-line BB),
// writing pgh0/pgh1 to LDS before the barrier -- NO cross-barrier registers.
// encT2 register staging dropped (R0 vs R4: worth 3%) to fund the headroom:
// scores k 0..63 stream from L2, k 64..127 from 128KB LDS. P1 = Wih only
// (half the loads). P5b serialization replaced by a replicated finale in
// P6; outputs emitted under S1. 7 barriers/step, none guarding serial code.
// Every accumulation chain keeps R4's exact order -> bit-identical
// (absmax 0.0); sampling is bit-exact threefry2x32.
// Spill tell: WRITE_SIZE >> 1 MB. Success: VGPR ~90-120, WRITE < 1 MB.
// ---------------------------------------------------------------------------

constexpr int B = 128, N = 512, H = 128, T = 32;
constexpr int G4 = 4 * H;  // 512
constexpr float TINYF = 1.17549435e-38f;  // np.finfo(float32).tiny

// ---- JAX threefry2x32 block cipher (20 rounds) ----------------------------
__host__ __device__ inline uint32_t rotl32(uint32_t v, int d) {
  return (v << d) | (v >> (32 - d));
}

__host__ __device__ inline void tf2x32(uint32_t k0, uint32_t k1,
                                       uint32_t x0, uint32_t x1,
                                       uint32_t& o0, uint32_t& o1) {
  uint32_t ks2 = k0 ^ k1 ^ 0x1BD11BDAu;
  x0 += k0; x1 += k1;
#define TF_R(r) x0 += x1; x1 = rotl32(x1, (r)); x1 ^= x0;
  TF_R(13) TF_R(15) TF_R(26) TF_R(6)
  x0 += k1; x1 += ks2 + 1u;
  TF_R(17) TF_R(29) TF_R(16) TF_R(24)
  x0 += ks2; x1 += k0 + 2u;
  TF_R(13) TF_R(15) TF_R(26) TF_R(6)
  x0 += k0; x1 += k1 + 3u;
  TF_R(17) TF_R(29) TF_R(16) TF_R(24)
  x0 += k1; x1 += ks2 + 4u;
  TF_R(13) TF_R(15) TF_R(26) TF_R(6)
  x0 += ks2; x1 += k0 + 5u;
#undef TF_R
  o0 = x0; o1 = x1;
}

struct KeyArgs { uint32_t k[2 * T]; };  // per-step subkeys, 256 B by value

// Host-side key chain (partitionable split): key0 = (0,42);
// new_key = E_key(0,0), sub = E_key(0,1).
static KeyArgs make_subkeys() {
  KeyArgs ka;
  uint32_t k0 = 0u, k1 = 42u;
  for (int t = 0; t < T; ++t) {
    uint32_t n0, n1, s0, s1;
    tf2x32(k0, k1, 0u, 0u, n0, n1);
    tf2x32(k0, k1, 0u, 1u, s0, s1);
    ka.k[2 * t] = s0; ka.k[2 * t + 1] = s1;
    k0 = n0; k1 = n1;
  }
  return ka;
}

// 32-bit draw i (of 65536) for this step's subkey: w0^w1 of E_sub(0, i)
__device__ inline uint32_t gumbel_bits(uint32_t sk0, uint32_t sk1, int i) {
  uint32_t o0, o1;
  tf2x32(sk0, sk1, 0u, (uint32_t)i, o0, o1);
  return o0 ^ o1;
}

// fast tanh for the score hot loop; abs err ~2e-7 (clamp avoids inf/inf NaN)
__device__ inline float fast_tanh(float x) {
  float cx = fminf(9.0f, fmaxf(-9.0f, x));
  float t = __expf(2.0f * cx);
  return (t - 1.0f) * __builtin_amdgcn_rcpf(t + 1.0f);
}

// ---- setup kernel 1: transpose weights for coalesced access ---------------
__global__ void k_transpose(const float* __restrict__ Wih, const float* __restrict__ Whh,
                            const float* __restrict__ W2, const float* __restrict__ W1,
                            float* __restrict__ WihT, float* __restrict__ WhhT,
                            float* __restrict__ W2T, float* __restrict__ W1T) {
  int i = blockIdx.x * blockDim.x + threadIdx.x;
  if (i < H * G4) {
    int h = i >> 9, j = i & (G4 - 1);
    WihT[i] = Wih[j * H + h];
  } else if (i < 2 * H * G4) {
    int q = i - H * G4; int h = q >> 9, j = q & (G4 - 1);
    WhhT[q] = Whh[j * H + h];
  } else if (i < 2 * H * G4 + H * H) {
    int q = i - 2 * H * G4; int h = q >> 7, k = q & (H - 1);
    W2T[q] = W2[k * H + h];
  } else if (i < 2 * H * G4 + 2 * H * H) {
    int q = i - 2 * H * G4 - H * H; int h = q >> 7, k = q & (H - 1);
    W1T[q] = W1[k * H + h];
  }
}

// ---- setup kernel 2: encT2[b,k,n] = sum_h enc[b,n,h] * W1[k,h] ------------
// (k-major output for the decode score SGEMV). 16 enc rows staged in LDS;
// 256 threads = 128 k x 2 n-groups; per-thread 8 consecutive n -> 2x float4.
__global__ __launch_bounds__(256) void k_enc_trans(const float* __restrict__ enc,
                                                   const float* __restrict__ W1T,
                                                   float* __restrict__ encT2) {
  __shared__ __align__(16) float es[16 * 128];  // 8 KB
  int blk = blockIdx.x;
  int b = blk >> 5;               // 32 blocks per batch
  int n0 = (blk & 31) << 4;       // 16 rows
  const float* src = enc + ((size_t)b * N + n0) * H;
  for (int i = threadIdx.x; i < 16 * 128; i += 256) es[i] = src[i];
  __syncthreads();
  int k = threadIdx.x & 127, ng = threadIdx.x >> 7;
  float acc[8] = {0.f, 0.f, 0.f, 0.f, 0.f, 0.f, 0.f, 0.f};
  for (int h = 0; h < H; h += 4) {
    float w0 = W1T[(h + 0) * H + k];   // coalesced (lanes = consecutive k)
    float w1 = W1T[(h + 1) * H + k];
    float w2 = W1T[(h + 2) * H + k];
    float w3 = W1T[(h + 3) * H + k];
#pragma unroll
    for (int j = 0; j < 8; ++j) {
      const float4 e = *(const float4*)&es[(ng * 8 + j) * 128 + h];  // broadcast
      acc[j] += w0 * e.x + w1 * e.y + w2 * e.z + w3 * e.w;
    }
  }
  float* dst = encT2 + (size_t)b * H * N + (size_t)k * N + n0 + ng * 8;
  ((float4*)dst)[0] = make_float4(acc[0], acc[1], acc[2], acc[3]);
  ((float4*)dst)[1] = make_float4(acc[4], acc[5], acc[6], acc[7]);
}

// ---- main fused decoder: 1 batch/block, 512 threads (8 waves) -------------
// Dynamic LDS (128 KB): e_lds[64][512] = encT2[b][64..127][:].
// Thread tid owns node n = tid AND gate j = tid.
__global__ __launch_bounds__(512)
__attribute__((amdgpu_waves_per_eu(2, 2))) void k_decode(
    const float* __restrict__ enc, const float* __restrict__ encT2,
    const float* __restrict__ WihT, const float* __restrict__ WhhT,
    const float* __restrict__ W2T,
    const float* __restrict__ bih, const float* __restrict__ bhh,
    const float* __restrict__ v,
    KeyArgs keys, float* __restrict__ out) {
  __shared__ __align__(16) float xs[H];      // dec_input
  __shared__ __align__(16) float hs[H];      // hx
  __shared__ __align__(16) float cs[H];      // cx
  __shared__ __align__(16) float dt[H];      // dec_trans = hx @ W2^T
  __shared__ __align__(16) float vv[H];
  __shared__ __align__(16) float bsum[G4];   // b_ih + b_hh
  __shared__ __align__(16) float pgx0[G4];   // Wih·x partial, h 0..63
  __shared__ __align__(16) float pgx1[G4];   // Wih·x partial, h 64..127
  __shared__ __align__(16) float pgh0[G4];   // Whh·h partial, h 0..63 (prefetched)
  __shared__ __align__(16) float pgh1[G4];   // Whh·h partial, h 64..127
  __shared__ float pdt[4][H];                // dt partials (and init-mean)
  __shared__ float sc[N];                    // masked scores
  __shared__ float wr_z[8], wr_m[8], wr_s[8];
  __shared__ int wr_i[8];

  extern __shared__ __align__(16) float e_lds[];  // 64*512 floats = 128 KB

  const int tid = threadIdx.x;
  const int b = blockIdx.x;
  const int lane = tid & 63;
  const int wave = tid >> 6;   // 0..7

  // ---- LDS-stage encT2[b][64..127][:] (128 KB), coalesced float4 ----------
  {
    const float4* src4 = (const float4*)(encT2 + (size_t)b * (H * N) + (size_t)64 * N);
    float4* dst4 = (float4*)e_lds;
#pragma unroll
    for (int i = 0; i < 16; ++i) dst4[tid + i * 512] = src4[tid + i * 512];
  }

  // ---- init: dec_input = mean_n enc[b,n,:]; h = c = 0; pgh = Whh·0 = +0 ---
  {
    int h = tid & 127, part = tid >> 7;
    float s = 0.f;
    const float* p = enc + ((size_t)b * N + part * 128) * H + h;
#pragma unroll 8
    for (int n = 0; n < 128; ++n) s += p[(size_t)n * H];  // coalesced across h
    pdt[part][h] = s;
    bsum[tid] = bih[tid] + bhh[tid];
    pgh0[tid] = 0.f;   // == Whh @ h(-1)=0 accumulated as in R4 (exact +0)
    pgh1[tid] = 0.f;
  }
  if (tid < 128) { hs[tid] = 0.f; cs[tid] = 0.f; vv[tid] = v[tid]; }
  __syncthreads();
  if (tid < 128)
    xs[tid] = (pdt[0][tid] + pdt[1][tid] + pdt[2][tid] + pdt[3][tid]) * (1.0f / N);
  bool masked = false;     // thread tid owns node tid
  int sidx_r = 0;          // previous step's sampled idx (uniform across thr)
  float smax_r = 0.f;      // previous step's score max
  __syncthreads();

  for (int t = 0; t < T; ++t) {
    // === S1: Wih·x only (Whh half was prefetched into pgh during S4(t-1)) ==
    // a0x: h 0..63 asc 4-grouped; a1x: h 64..127 -- bitwise == R4's chains.
    // Thread 0 also emits the previous step's outputs (hidden under GEMV).
    {
      if (tid == 0 && t > 0) {
        float sum = wr_s[0] + wr_s[1] + wr_s[2] + wr_s[3]
                  + wr_s[4] + wr_s[5] + wr_s[6] + wr_s[7];
        float p = expf(sc[sidx_r] - smax_r) / sum;
        out[(size_t)b * T + (t - 1)] = (float)sidx_r;
        out[(size_t)B * T + (size_t)b * T + (t - 1)] = logf(p + 1e-9f);
      }
      const float* wi = WihT + tid;
      float a0x = 0.f, a1x = 0.f;
#pragma unroll 8
      for (int h = 0; h < 64; h += 4) {
        const float4 xv = *(const float4*)&xs[h];
        a0x += wi[(size_t)(h + 0) * G4] * xv.x;
        a0x += wi[(size_t)(h + 1) * G4] * xv.y;
        a0x += wi[(size_t)(h + 2) * G4] * xv.z;
        a0x += wi[(size_t)(h + 3) * G4] * xv.w;
      }
#pragma unroll 8
      for (int h = 64; h < 128; h += 4) {
        const float4 xv = *(const float4*)&xs[h];
        a1x += wi[(size_t)(h + 0) * G4] * xv.x;
        a1x += wi[(size_t)(h + 1) * G4] * xv.y;
        a1x += wi[(size_t)(h + 2) * G4] * xv.z;
        a1x += wi[(size_t)(h + 3) * G4] * xv.w;
      }
      pgx0[tid] = a0x;
      pgx1[tid] = a1x;
    }
    __syncthreads();
    // === S2: cell update (torch gate order i,f,g,o) ========================
    // gate = ((a0x+a0h)+(a1x+a1h)) + bsum -- bitwise == R4.
    if (tid < 128) {
      float gi = ((pgx0[tid] + pgh0[tid]) + (pgx1[tid] + pgh1[tid])) + bsum[tid];
      float gf = ((pgx0[H + tid] + pgh0[H + tid]) + (pgx1[H + tid] + pgh1[H + tid])) + bsum[H + tid];
      float gg = ((pgx0[2 * H + tid] + pgh0[2 * H + tid]) + (pgx1[2 * H + tid] + pgh1[2 * H + tid])) + bsum[2 * H + tid];
      float go = ((pgx0[3 * H + tid] + pgh0[3 * H + tid]) + (pgx1[3 * H + tid] + pgh1[3 * H + tid])) + bsum[3 * H + tid];
      gi = 1.0f / (1.0f + expf(-gi));
      gf = 1.0f / (1.0f + expf(-gf));
      gg = tanhf(gg);
      go = 1.0f / (1.0f + expf(-go));
      float c = gf * cs[tid] + gi * gg;
      cs[tid] = c;
      hs[tid] = go * tanhf(c);   // hs is now h(t+1): S4 may prefetch Whh·h
    }
    __syncthreads();
    // === S3: dt partials (R4's P3 verbatim) ================================
    {
      int k = tid & 127, part = tid >> 7;
      const float* w2 = W2T + (size_t)(part * 32) * H + k;
      const int hbp = part * 32;
      float a = 0.f;
#pragma unroll 8
      for (int h = 0; h < 32; h += 4) {
        const float4 hv = *(const float4*)&hs[hbp + h];
        a += w2[(size_t)(h + 0) * H] * hv.x;
        a += w2[(size_t)(h + 1) * H] * hv.y;
        a += w2[(size_t)(h + 2) * H] * hv.z;
        a += w2[(size_t)(h + 3) * H] * hv.w;
      }
      pdt[part][k] = a;
    }
    __syncthreads();
    if (tid < 128) dt[tid] = pdt[0][tid] + pdt[1][tid] + pdt[2][tid] + pdt[3][tid];
    __syncthreads();
    // === S4: scores FUSED with next-step Whh·h prefetch ====================
    // Scores: k 0..63 from L2 (same values R4 held in er regs -> identical
    // bits), k 64..127 from LDS; even/odd-k a0/a1 then c0/c1, final
    // (a0+a1)+(c0+c1) == R4. Whh: a0h h0..63, a1h h64..127, asc 4-grouped
    // == R4's chains; results go straight to pgh LDS (no cross-barrier regs).
    // One straight-line BB: scheduler hoists Whh loads under tanh chains.
    float s;
    {
      const float* eg = encT2 + (size_t)b * (H * N) + tid;
      const float* el = e_lds + tid;
      const float* wh = WhhT + tid;
      float a0h = 0.f, a1h = 0.f;
      float a0 = 0.f, a1 = 0.f, c0 = 0.f, c1 = 0.f;
#pragma unroll
      for (int m = 0; m < 4; ++m) {
        const int base = m * 16;
#pragma unroll
        for (int q = 0; q < 16; q += 4) {   // Whh h = base..base+15 -> a0h
          const int h = base + q;
          const float4 hv = *(const float4*)&hs[h];
          a0h += wh[(size_t)(h + 0) * G4] * hv.x;
          a0h += wh[(size_t)(h + 1) * G4] * hv.y;
          a0h += wh[(size_t)(h + 2) * G4] * hv.z;
          a0h += wh[(size_t)(h + 3) * G4] * hv.w;
        }
#pragma unroll
        for (int q = 0; q < 16; q += 4) {   // scores k = base..base+15 (L2)
          const int k = base + q;
          const float e0 = eg[(size_t)(k + 0) * N];
          const float e1 = eg[(size_t)(k + 1) * N];
          const float e2 = eg[(size_t)(k + 2) * N];
          const float e3 = eg[(size_t)(k + 3) * N];
          const float4 dv = *(const float4*)&dt[k];
          const float4 vw = *(const float4*)&vv[k];
          a0 += vw.x * fast_tanh(e0 + dv.x);
          a1 += vw.y * fast_tanh(e1 + dv.y);
          a0 += vw.z * fast_tanh(e2 + dv.z);
          a1 += vw.w * fast_tanh(e3 + dv.w);
        }
      }
#pragma unroll
      for (int m = 4; m < 8; ++m) {
        const int base = m * 16;
#pragma unroll
        for (int q = 0; q < 16; q += 4) {   // Whh h = base..base+15 -> a1h
          const int h = base + q;
          const float4 hv = *(const float4*)&hs[h];
          a1h += wh[(size_t)(h + 0) * G4] * hv.x;
          a1h += wh[(size_t)(h + 1) * G4] * hv.y;
          a1h += wh[(size_t)(h + 2) * G4] * hv.z;
          a1h += wh[(size_t)(h + 3) * G4] * hv.w;
        }
#pragma unroll
        for (int q = 0; q < 16; q += 4) {   // scores k = base..base+15 (LDS)
          const int k = base + q;
          const float e0 = el[(k - 64 + 0) * 512];
          const float e1 = el[(k - 64 + 1) * 512];
          const float e2 = el[(k - 64 + 2) * 512];
          const float e3 = el[(k - 64 + 3) * 512];
          const float4 dv = *(const float4*)&dt[k];
          const float4 vw = *(const float4*)&vv[k];
          c0 += vw.x * fast_tanh(e0 + dv.x);
          c1 += vw.y * fast_tanh(e1 + dv.y);
          c0 += vw.z * fast_tanh(e2 + dv.z);
          c1 += vw.w * fast_tanh(e3 + dv.w);
        }
      }
      pgh0[tid] = a0h;   // next step's gate halves, written before barrier
      pgh1[tid] = a1h;
      const float s_score = (a0 + a1) + (c0 + c1);
      s = masked ? -INFINITY : s_score;
      sc[tid] = s;
      // gumbel + per-wave argmax/max (R4's P5a verbatim)
      uint32_t bits = gumbel_bits(keys.k[2 * t], keys.k[2 * t + 1], b * N + tid);
      float f = __uint_as_float((bits >> 9) | 0x3f800000u) - 1.0f;
      float u = fmaxf(TINYF, f + TINYF);
      float g = -logf(-logf(u));  // accurate logf (hw log2 too sloppy near u~1)
      float z = s + g;
      int zi = tid;
      float m = s;
#pragma unroll
      for (int d = 32; d >= 1; d >>= 1) {
        float oz = __shfl_xor(z, d);
        int oi = __shfl_xor(zi, d);
        float om = __shfl_xor(m, d);
        if (oz > z || (oz == z && oi < zi)) { z = oz; zi = oi; }  // first-idx ties
        m = fmaxf(m, om);
      }
      if (lane == 0) { wr_z[wave] = z; wr_i[wave] = zi; wr_m[wave] = m; }
    }
    __syncthreads();
    // === S5: replicated finale (== R4's P5b chain) + softmax + select ======
    {
      float bz = wr_z[0]; int bi = wr_i[0]; float bm = wr_m[0];
#pragma unroll
      for (int w = 1; w < 8; ++w) {
        if (wr_z[w] > bz || (wr_z[w] == bz && wr_i[w] < bi)) { bz = wr_z[w]; bi = wr_i[w]; }
        bm = fmaxf(bm, wr_m[w]);
      }
      sidx_r = bi; smax_r = bm;
      float xnew = 0.f;
      if (tid < 128) xnew = enc[((size_t)b * N + bi) * H + tid];  // issue early
      float e = expf(s - bm);  // masked: exp(-inf) = 0
#pragma unroll
      for (int d = 32; d >= 1; d >>= 1) e += __shfl_xor(e, d);
      if (lane == 0) wr_s[wave] = e;
      if (tid == bi) masked = true;
      if (tid < 128) xs[tid] = xnew;
    }
    __syncthreads();
  }
  // epilogue: outputs for the final step
  if (tid == 0) {
    float sum = wr_s[0] + wr_s[1] + wr_s[2] + wr_s[3]
              + wr_s[4] + wr_s[5] + wr_s[6] + wr_s[7];
    float p = expf(sc[sidx_r] - smax_r) / sum;
    out[(size_t)b * T + (T - 1)] = (float)sidx_r;
    out[(size_t)B * T + (size_t)b * T + (T - 1)] = logf(p + 1e-9f);
  }
}

// ---------------------------------------------------------------------------
extern "C" void kernel_launch(void* const* d_in, const int* in_sizes, int n_in,
                              void* d_out, int out_size, void* d_ws, size_t ws_size,
                              hipStream_t stream) {
  (void)in_sizes; (void)n_in; (void)out_size; (void)ws_size;
  const float* enc = (const float*)d_in[0];
  const float* Wih = (const float*)d_in[1];
  const float* Whh = (const float*)d_in[2];
  const float* bih = (const float*)d_in[3];
  const float* bhh = (const float*)d_in[4];
  const float* W1  = (const float*)d_in[5];
  const float* W2  = (const float*)d_in[6];
  const float* v   = (const float*)d_in[7];
  float* out = (float*)d_out;
  float* ws = (float*)d_ws;

  // ws layout (floats): WihT 65536 | WhhT 65536 | W2T 16384 | W1T 16384 | encT2 8388608
  float* WihT  = ws;
  float* WhhT  = ws + 65536;
  float* W2T   = ws + 131072;
  float* W1T   = ws + 147456;
  float* encT2 = ws + 163840;   // [b][k][n], ~33.5 MB

  KeyArgs keys = make_subkeys();  // pure host arithmetic: capture-safe

  // allow 128KB dynamic LDS for k_decode (host-side attr; capture-safe)
  static bool lds_attr_set = false;
  if (!lds_attr_set) {
    (void)hipFuncSetAttribute(reinterpret_cast<const void*>(k_decode),
                              hipFuncAttributeMaxDynamicSharedMemorySize, 131072);
    lds_attr_set = true;
  }

  k_transpose<<<640, 256, 0, stream>>>(Wih, Whh, W2, W1, WihT, WhhT, W2T, W1T);
  k_enc_trans<<<B * N / 16, 256, 0, stream>>>(enc, W1T, encT2);
  k_decode<<<B, 512, 131072, stream>>>(enc, encT2, WihT, WhhT, W2T,
                                       bih, bhh, v, keys, out);
}

// Round 9
// 1649.225 us; speedup vs baseline: 1.7479x; 1.4361x over previous
//
#include <hip/hip_runtime.h>
#include <cstdint>
#include <cstddef>

// ---------------------------------------------------------------------------
// Pointer-network decoder: B=128 batches decode T=32 steps over N=512 nodes.
// One block per batch (grid 128, 512 threads, 8 waves) -- R4's PROVEN
// spill-free envelope (wg=512 + waves_per_eu(2,2) -> 128 VGPRs honored,
// WRITE_SIZE 32KB, FETCH 35MB, 484us).
// Round 11 = R4 chassis + two surgical changes (R6/R7/R8 restructures all
// regressed by breaking the compiler's per-phase software pipelining):
//  (1) float4-packed weights (WihT4/WhhT4/W2T4: 4 consecutive h per float4)
//      -> P1: 64 float4 loads/thread instead of 256 scalar (same bytes, 4x
//      fewer instructions, 4x bytes per outstanding load). FMA order per
//      accumulator unchanged (ascending h, 4-grouped) -> bit-identical.
//  (2) replicated argmax finale (every thread redoes the 8-way chain) fusing
//      P5b+P6+P6b into one phase: 8 -> 6 barriers/step, no single-thread
//      serial sections on the path; outputs emitted under S1's GEMV.
// encT2 placement identical to R4: k 0..63 in 16 named float4 regs (er),
// k 64..127 in 128KB dynamic LDS. All accumulation chains keep R4's exact
// order -> bit-identical outputs (absmax 0.0). threefry sampling bit-exact.
// Spill tell: WRITE_SIZE >> 1MB. L2-regime tell: FETCH ~35MB (not 700MB).
// ---------------------------------------------------------------------------

constexpr int B = 128, N = 512, H = 128, T = 32;
constexpr int G4 = 4 * H;  // 512
constexpr float TINYF = 1.17549435e-38f;  // np.finfo(float32).tiny

// ---- JAX threefry2x32 block cipher (20 rounds) ----------------------------
__host__ __device__ inline uint32_t rotl32(uint32_t v, int d) {
  return (v << d) | (v >> (32 - d));
}

__host__ __device__ inline void tf2x32(uint32_t k0, uint32_t k1,
                                       uint32_t x0, uint32_t x1,
                                       uint32_t& o0, uint32_t& o1) {
  uint32_t ks2 = k0 ^ k1 ^ 0x1BD11BDAu;
  x0 += k0; x1 += k1;
#define TF_R(r) x0 += x1; x1 = rotl32(x1, (r)); x1 ^= x0;
  TF_R(13) TF_R(15) TF_R(26) TF_R(6)
  x0 += k1; x1 += ks2 + 1u;
  TF_R(17) TF_R(29) TF_R(16) TF_R(24)
  x0 += ks2; x1 += k0 + 2u;
  TF_R(13) TF_R(15) TF_R(26) TF_R(6)
  x0 += k0; x1 += k1 + 3u;
  TF_R(17) TF_R(29) TF_R(16) TF_R(24)
  x0 += k1; x1 += ks2 + 4u;
  TF_R(13) TF_R(15) TF_R(26) TF_R(6)
  x0 += ks2; x1 += k0 + 5u;
#undef TF_R
  o0 = x0; o1 = x1;
}

struct KeyArgs { uint32_t k[2 * T]; };  // per-step subkeys, 256 B by value

// Host-side key chain (partitionable split): key0 = (0,42);
// new_key = E_key(0,0), sub = E_key(0,1).
static KeyArgs make_subkeys() {
  KeyArgs ka;
  uint32_t k0 = 0u, k1 = 42u;
  for (int t = 0; t < T; ++t) {
    uint32_t n0, n1, s0, s1;
    tf2x32(k0, k1, 0u, 0u, n0, n1);
    tf2x32(k0, k1, 0u, 1u, s0, s1);
    ka.k[2 * t] = s0; ka.k[2 * t + 1] = s1;
    k0 = n0; k1 = n1;
  }
  return ka;
}

// 32-bit draw i (of 65536) for this step's subkey: w0^w1 of E_sub(0, i)
__device__ inline uint32_t gumbel_bits(uint32_t sk0, uint32_t sk1, int i) {
  uint32_t o0, o1;
  tf2x32(sk0, sk1, 0u, (uint32_t)i, o0, o1);
  return o0 ^ o1;
}

// fast tanh for the score hot loop; abs err ~2e-7 (clamp avoids inf/inf NaN)
__device__ inline float fast_tanh(float x) {
  float cx = fminf(9.0f, fmaxf(-9.0f, x));
  float t = __expf(2.0f * cx);
  return (t - 1.0f) * __builtin_amdgcn_rcpf(t + 1.0f);
}

// ---- setup kernel 1: pack weights for the decode layouts ------------------
// WihT4/WhhT4 (float4-packed): flat[(h4*512 + j)*4 + c] = W[j][4*h4 + c]
// W2T4: flat[(h4*128 + k)*4 + c] = W2[k][4*h4 + c]
// W1T (unchanged, for k_enc_trans): W1T[h*H + k] = W1[k][h]
__global__ void k_transpose(const float* __restrict__ Wih, const float* __restrict__ Whh,
                            const float* __restrict__ W2, const float* __restrict__ W1,
                            float* __restrict__ WihT, float* __restrict__ WhhT,
                            float* __restrict__ W2T, float* __restrict__ W1T) {
  int i = blockIdx.x * blockDim.x + threadIdx.x;
  if (i < H * G4) {
    int c = i & 3, j = (i >> 2) & 511, h4 = i >> 11;
    WihT[i] = Wih[j * H + h4 * 4 + c];
  } else if (i < 2 * H * G4) {
    int q = i - H * G4;
    int c = q & 3, j = (q >> 2) & 511, h4 = q >> 11;
    WhhT[q] = Whh[j * H + h4 * 4 + c];
  } else if (i < 2 * H * G4 + H * H) {
    int q = i - 2 * H * G4;
    int c = q & 3, k = (q >> 2) & 127, h4 = q >> 9;
    W2T[q] = W2[k * H + h4 * 4 + c];
  } else if (i < 2 * H * G4 + 2 * H * H) {
    int q = i - 2 * H * G4 - H * H; int h = q >> 7, k = q & (H - 1);
    W1T[q] = W1[k * H + h];
  }
}

// ---- setup kernel 2: encT2[b,k,n] = sum_h enc[b,n,h] * W1[k,h] ------------
// (k-major output for the decode score SGEMV). 16 enc rows staged in LDS;
// 256 threads = 128 k x 2 n-groups; per-thread 8 consecutive n -> 2x float4.
__global__ __launch_bounds__(256) void k_enc_trans(const float* __restrict__ enc,
                                                   const float* __restrict__ W1T,
                                                   float* __restrict__ encT2) {
  __shared__ __align__(16) float es[16 * 128];  // 8 KB
  int blk = blockIdx.x;
  int b = blk >> 5;               // 32 blocks per batch
  int n0 = (blk & 31) << 4;       // 16 rows
  const float* src = enc + ((size_t)b * N + n0) * H;
  for (int i = threadIdx.x; i < 16 * 128; i += 256) es[i] = src[i];
  __syncthreads();
  int k = threadIdx.x & 127, ng = threadIdx.x >> 7;
  float acc[8] = {0.f, 0.f, 0.f, 0.f, 0.f, 0.f, 0.f, 0.f};
  for (int h = 0; h < H; h += 4) {
    float w0 = W1T[(h + 0) * H + k];   // coalesced (lanes = consecutive k)
    float w1 = W1T[(h + 1) * H + k];
    float w2 = W1T[(h + 2) * H + k];
    float w3 = W1T[(h + 3) * H + k];
#pragma unroll
    for (int j = 0; j < 8; ++j) {
      const float4 e = *(const float4*)&es[(ng * 8 + j) * 128 + h];  // broadcast
      acc[j] += w0 * e.x + w1 * e.y + w2 * e.z + w3 * e.w;
    }
  }
  float* dst = encT2 + (size_t)b * H * N + (size_t)k * N + n0 + ng * 8;
  ((float4*)dst)[0] = make_float4(acc[0], acc[1], acc[2], acc[3]);
  ((float4*)dst)[1] = make_float4(acc[4], acc[5], acc[6], acc[7]);
}

#define REP16(M) M(0) M(1) M(2) M(3) M(4) M(5) M(6) M(7) \
                 M(8) M(9) M(10) M(11) M(12) M(13) M(14) M(15)

// ---- main fused decoder: 1 batch/block, 512 threads (8 waves) -------------
// Dynamic LDS (128 KB): e_lds[64][512] = encT2[b][64..127][:] (k-half 1).
// k-half 0 lives in 16 named float4 registers per thread (thread = node n).
__global__ __launch_bounds__(512)
__attribute__((amdgpu_waves_per_eu(2, 2))) void k_decode(
    const float* __restrict__ enc, const float* __restrict__ encT2,
    const float* __restrict__ WihT, const float* __restrict__ WhhT,
    const float* __restrict__ W2T,
    const float* __restrict__ bih, const float* __restrict__ bhh,
    const float* __restrict__ v,
    KeyArgs keys, float* __restrict__ out) {
  __shared__ __align__(16) float xs[H];     // dec_input
  __shared__ __align__(16) float hs[H];     // hx
  __shared__ __align__(16) float cs[H];     // cx
  __shared__ __align__(16) float dt[H];     // dec_trans = hx @ W2^T
  __shared__ __align__(16) float vv[H];
  __shared__ __align__(16) float bsum[G4];  // b_ih + b_hh
  __shared__ float pg[G4];                  // gate pre-activations (sans bias)
  __shared__ float pdt[4][H];               // dt partials (and init-mean)
  __shared__ float sc[N];                   // masked scores
  __shared__ float wr_z[8], wr_m[8], wr_s[8];
  __shared__ int wr_i[8];

  extern __shared__ __align__(16) float e_lds[];  // 64*512 floats = 128 KB

  const int tid = threadIdx.x;   // owns node n = tid and gate j = tid
  const int b = blockIdx.x;
  const int lane = tid & 63;
  const int wave = tid >> 6;     // 0..7

  // ---- register-stage encT2[b][0..63][tid]: 16 named float4 (no alloca) ---
  const float* ep = encT2 + (size_t)b * (H * N) + tid;
#define ERLD(i) float4 er##i = make_float4(ep[(size_t)(4*i+0) * N], \
                                           ep[(size_t)(4*i+1) * N], \
                                           ep[(size_t)(4*i+2) * N], \
                                           ep[(size_t)(4*i+3) * N]);
  REP16(ERLD)
#undef ERLD

  // ---- LDS-stage encT2[b][64..127][:] (128 KB), coalesced float4 ----------
  {
    const float4* src4 = (const float4*)(encT2 + (size_t)b * (H * N) + (size_t)64 * N);
    float4* dst4 = (float4*)e_lds;
#pragma unroll
    for (int i = 0; i < 16; ++i) dst4[tid + i * 512] = src4[tid + i * 512];
  }

  // ---- init: dec_input = mean_n enc[b,n,:]; h = c = 0 ----
  {
    int h = tid & 127, part = tid >> 7;
    float s = 0.f;
    const float* p = enc + ((size_t)b * N + part * 128) * H + h;
#pragma unroll 8
    for (int n = 0; n < 128; ++n) s += p[(size_t)n * H];  // coalesced across h
    pdt[part][h] = s;
    bsum[tid] = bih[tid] + bhh[tid];
  }
  if (tid < 128) { hs[tid] = 0.f; cs[tid] = 0.f; vv[tid] = v[tid]; }
  __syncthreads();
  if (tid < 128)
    xs[tid] = (pdt[0][tid] + pdt[1][tid] + pdt[2][tid] + pdt[3][tid]) * (1.0f / N);
  bool masked = false;     // thread tid owns node tid
  int sidx_r = 0;          // previous step's sampled idx (uniform across thr)
  float smax_r = 0.f;      // previous step's score max
  __syncthreads();

  for (int t = 0; t < T; ++t) {
    // === S1: gates, float4-packed weights. Thread 0 also emits the previous
    // step's outputs (hidden under the GEMV). Accumulator chains: a0x/a0h
    // h 0..63, a1x/a1h h 64..127, ascending 4-grouped; combine
    // (a0x+a0h)+(a1x+a1h) -- all bitwise == R4. =============================
    {
      if (tid == 0 && t > 0) {
        float sum = wr_s[0] + wr_s[1] + wr_s[2] + wr_s[3]
                  + wr_s[4] + wr_s[5] + wr_s[6] + wr_s[7];
        float p = expf(sc[sidx_r] - smax_r) / sum;
        out[(size_t)b * T + (t - 1)] = (float)sidx_r;
        out[(size_t)B * T + (size_t)b * T + (t - 1)] = logf(p + 1e-9f);
      }
      const float4* wi4 = (const float4*)WihT + tid;  // [h4*512 + tid]
      const float4* wh4 = (const float4*)WhhT + tid;
      float a0x = 0.f, a0h = 0.f, a1x = 0.f, a1h = 0.f;
#pragma unroll
      for (int h4 = 0; h4 < 16; ++h4) {
        const float4 w = wi4[(size_t)h4 * 512];
        const float4 u = wh4[(size_t)h4 * 512];
        const float4 xv = *(const float4*)&xs[h4 * 4];
        const float4 hv = *(const float4*)&hs[h4 * 4];
        a0x += w.x * xv.x; a0x += w.y * xv.y; a0x += w.z * xv.z; a0x += w.w * xv.w;
        a0h += u.x * hv.x; a0h += u.y * hv.y; a0h += u.z * hv.z; a0h += u.w * hv.w;
      }
#pragma unroll
      for (int h4 = 16; h4 < 32; ++h4) {
        const float4 w = wi4[(size_t)h4 * 512];
        const float4 u = wh4[(size_t)h4 * 512];
        const float4 xv = *(const float4*)&xs[h4 * 4];
        const float4 hv = *(const float4*)&hs[h4 * 4];
        a1x += w.x * xv.x; a1x += w.y * xv.y; a1x += w.z * xv.z; a1x += w.w * xv.w;
        a1h += u.x * hv.x; a1h += u.y * hv.y; a1h += u.z * hv.z; a1h += u.w * hv.w;
      }
      pg[tid] = (a0x + a0h) + (a1x + a1h);
    }
    __syncthreads();
    // === S2: cell update (torch gate order i,f,g,o) ========================
    if (tid < 128) {
      float gi = pg[tid] + bsum[tid];
      float gf = pg[H + tid] + bsum[H + tid];
      float gg = pg[2 * H + tid] + bsum[2 * H + tid];
      float go = pg[3 * H + tid] + bsum[3 * H + tid];
      gi = 1.0f / (1.0f + expf(-gi));
      gf = 1.0f / (1.0f + expf(-gf));
      gg = tanhf(gg);
      go = 1.0f / (1.0f + expf(-go));
      float c = gf * cs[tid] + gi * gg;
      cs[tid] = c;
      hs[tid] = go * tanhf(c);
    }
    __syncthreads();
    // === S3: dt partials, float4-packed W2T (k = tid&127, 32 h each) =======
    {
      int k = tid & 127, part = tid >> 7;
      const float4* w24 = (const float4*)W2T + (size_t)(part * 8) * H + k;
      float a = 0.f;
#pragma unroll
      for (int q = 0; q < 8; ++q) {
        const float4 u = w24[(size_t)q * H];
        const float4 hv = *(const float4*)&hs[part * 32 + q * 4];
        a += u.x * hv.x; a += u.y * hv.y; a += u.z * hv.z; a += u.w * hv.w;
      }
      pdt[part][k] = a;
    }
    __syncthreads();
    if (tid < 128) dt[tid] = pdt[0][tid] + pdt[1][tid] + pdt[2][tid] + pdt[3][tid];
    __syncthreads();
    // === S4: scores (R4's P4+P5a verbatim) =================================
    // k-half 0 from registers, k-half 1 from LDS; accumulator pattern
    // (a0 = k%4 in {0,2}, a1 = {1,3}, ascending k, per half, then
    // (a0+a1)+(b0+b1)) is bitwise == R4.
    float s;
    {
      float a0 = 0.f, a1 = 0.f;
#define P4A(i) { const float4 dv = *(const float4*)&dt[4 * i];              \
                 const float4 vw = *(const float4*)&vv[4 * i];              \
                 a0 += vw.x * fast_tanh(er##i.x + dv.x);                    \
                 a1 += vw.y * fast_tanh(er##i.y + dv.y);                    \
                 a0 += vw.z * fast_tanh(er##i.z + dv.z);                    \
                 a1 += vw.w * fast_tanh(er##i.w + dv.w); }
      REP16(P4A)
#undef P4A
      float b0 = 0.f, b1 = 0.f;
#pragma unroll
      for (int k4 = 0; k4 < 64; k4 += 4) {
        const float e0 = e_lds[(k4 + 0) * N + tid];
        const float e1 = e_lds[(k4 + 1) * N + tid];
        const float e2 = e_lds[(k4 + 2) * N + tid];
        const float e3 = e_lds[(k4 + 3) * N + tid];
        const float4 dv = *(const float4*)&dt[64 + k4];
        const float4 vw = *(const float4*)&vv[64 + k4];
        b0 += vw.x * fast_tanh(e0 + dv.x);
        b1 += vw.y * fast_tanh(e1 + dv.y);
        b0 += vw.z * fast_tanh(e2 + dv.z);
        b1 += vw.w * fast_tanh(e3 + dv.w);
      }
      const float s_score = (a0 + a1) + (b0 + b1);
      s = masked ? -INFINITY : s_score;
      sc[tid] = s;
      uint32_t bits = gumbel_bits(keys.k[2 * t], keys.k[2 * t + 1], b * N + tid);
      // XLA uniform(minval=tiny, maxval=1): bits->[1,2)->-1, +tiny, max
      float f = __uint_as_float((bits >> 9) | 0x3f800000u) - 1.0f;
      float u = fmaxf(TINYF, f + TINYF);
      float g = -logf(-logf(u));  // accurate logf (hw log2 too sloppy near u~1)
      float z = s + g;
      int zi = tid;
      float m = s;
#pragma unroll
      for (int d = 32; d >= 1; d >>= 1) {
        float oz = __shfl_xor(z, d);
        int oi = __shfl_xor(zi, d);
        float om = __shfl_xor(m, d);
        if (oz > z || (oz == z && oi < zi)) { z = oz; zi = oi; }  // first-idx ties
        m = fmaxf(m, om);
      }
      if (lane == 0) { wr_z[wave] = z; wr_i[wave] = zi; wr_m[wave] = m; }
    }
    __syncthreads();
    // === S5: replicated finale (== R4's P5b chain in every thread) +
    //         softmax partials + mask + next dec_input ======================
    {
      float bz = wr_z[0]; int bi = wr_i[0]; float bm = wr_m[0];
#pragma unroll
      for (int w = 1; w < 8; ++w) {
        if (wr_z[w] > bz || (wr_z[w] == bz && wr_i[w] < bi)) { bz = wr_z[w]; bi = wr_i[w]; }
        bm = fmaxf(bm, wr_m[w]);
      }
      sidx_r = bi; smax_r = bm;
      float xnew = 0.f;
      if (tid < 128) xnew = enc[((size_t)b * N + bi) * H + tid];  // issue early
      float e = expf(s - bm);  // masked: exp(-inf) = 0
#pragma unroll
      for (int d = 32; d >= 1; d >>= 1) e += __shfl_xor(e, d);
      if (lane == 0) wr_s[wave] = e;
      if (tid == bi) masked = true;
      if (tid < 128) xs[tid] = xnew;
    }
    __syncthreads();
  }
  // epilogue: outputs for the final step
  if (tid == 0) {
    float sum = wr_s[0] + wr_s[1] + wr_s[2] + wr_s[3]
              + wr_s[4] + wr_s[5] + wr_s[6] + wr_s[7];
    float p = expf(sc[sidx_r] - smax_r) / sum;
    out[(size_t)b * T + (T - 1)] = (float)sidx_r;
    out[(size_t)B * T + (size_t)b * T + (T - 1)] = logf(p + 1e-9f);
  }
}

// ---------------------------------------------------------------------------
extern "C" void kernel_launch(void* const* d_in, const int* in_sizes, int n_in,
                              void* d_out, int out_size, void* d_ws, size_t ws_size,
                              hipStream_t stream) {
  (void)in_sizes; (void)n_in; (void)out_size; (void)ws_size;
  const float* enc = (const float*)d_in[0];
  const float* Wih = (const float*)d_in[1];
  const float* Whh = (const float*)d_in[2];
  const float* bih = (const float*)d_in[3];
  const float* bhh = (const float*)d_in[4];
  const float* W1  = (const float*)d_in[5];
  const float* W2  = (const float*)d_in[6];
  const float* v   = (const float*)d_in[7];
  float* out = (float*)d_out;
  float* ws = (float*)d_ws;

  // ws layout (floats): WihT4 65536 | WhhT4 65536 | W2T4 16384 | W1T 16384 | encT2 8388608
  float* WihT  = ws;
  float* WhhT  = ws + 65536;
  float* W2T   = ws + 131072;
  float* W1T   = ws + 147456;
  float* encT2 = ws + 163840;   // [b][k][n], ~33.5 MB

  KeyArgs keys = make_subkeys();  // pure host arithmetic: capture-safe

  // allow 128KB dynamic LDS for k_decode (host-side attr; capture-safe)
  static bool lds_attr_set = false;
  if (!lds_attr_set) {
    (void)hipFuncSetAttribute(reinterpret_cast<const void*>(k_decode),
                              hipFuncAttributeMaxDynamicSharedMemorySize, 131072);
    lds_attr_set = true;
  }

  k_transpose<<<640, 256, 0, stream>>>(Wih, Whh, W2, W1, WihT, WhhT, W2T, W1T);
  k_enc_trans<<<B * N / 16, 256, 0, stream>>>(enc, W1T, encT2);
  k_decode<<<B, 512, 131072, stream>>>(enc, encT2, WihT, WhhT, W2T,
                                       bih, bhh, v, keys, out);
}

// Round 10
// 580.475 us; speedup vs baseline: 4.9662x; 2.8412x over previous
//
#include <hip/hip_runtime.h>
#include <cstdint>
#include <cstddef>

// ---------------------------------------------------------------------------
// Pointer-network decoder: B=128 batches decode T=32 steps over N=512 nodes.
// One block per batch (grid 128, 512 threads, 8 waves).
// Round 12 = R4 chassis RECONSTRUCTED BYTE-FOR-BYTE (scalar weight loads --
// R9 proved float4-packing breaks L2 residency: FETCH 35MB -> 1.1GB; R7/R8
// proved fusion/specialization break compiler pipelining) + ONE change that
// touches no global-memory stream: P5b+P6+P6b merged into a single phase S5
// with a replicated 8-way argmax finale (every thread redoes the chain ->
// identical bits), and the previous step's outputs emitted by thread 0
// under S1's GEMV. 8 -> 6 barriers/step, no single-thread serial phases.
// encT2: k 0..63 in 16 named float4 regs (er), k 64..127 in 128KB dyn LDS.
// wg=512 + waves_per_eu(2,2): the proven spill-free 128-VGPR envelope.
// All accumulation chains keep R4's exact order -> bit-identical outputs
// (absmax 0.0; R9 already validated this exact S5/emission structure).
// Tells: FETCH ~35MB (L2-resident weights), WRITE ~32KB (no spill).
// ---------------------------------------------------------------------------

constexpr int B = 128, N = 512, H = 128, T = 32;
constexpr int G4 = 4 * H;  // 512
constexpr float TINYF = 1.17549435e-38f;  // np.finfo(float32).tiny

// ---- JAX threefry2x32 block cipher (20 rounds) ----------------------------
__host__ __device__ inline uint32_t rotl32(uint32_t v, int d) {
  return (v << d) | (v >> (32 - d));
}

__host__ __device__ inline void tf2x32(uint32_t k0, uint32_t k1,
                                       uint32_t x0, uint32_t x1,
                                       uint32_t& o0, uint32_t& o1) {
  uint32_t ks2 = k0 ^ k1 ^ 0x1BD11BDAu;
  x0 += k0; x1 += k1;
#define TF_R(r) x0 += x1; x1 = rotl32(x1, (r)); x1 ^= x0;
  TF_R(13) TF_R(15) TF_R(26) TF_R(6)
  x0 += k1; x1 += ks2 + 1u;
  TF_R(17) TF_R(29) TF_R(16) TF_R(24)
  x0 += ks2; x1 += k0 + 2u;
  TF_R(13) TF_R(15) TF_R(26) TF_R(6)
  x0 += k0; x1 += k1 + 3u;
  TF_R(17) TF_R(29) TF_R(16) TF_R(24)
  x0 += k1; x1 += ks2 + 4u;
  TF_R(13) TF_R(15) TF_R(26) TF_R(6)
  x0 += ks2; x1 += k0 + 5u;
#undef TF_R
  o0 = x0; o1 = x1;
}

struct KeyArgs { uint32_t k[2 * T]; };  // per-step subkeys, 256 B by value

// Host-side key chain (partitionable split): key0 = (0,42);
// new_key = E_key(0,0), sub = E_key(0,1).
static KeyArgs make_subkeys() {
  KeyArgs ka;
  uint32_t k0 = 0u, k1 = 42u;
  for (int t = 0; t < T; ++t) {
    uint32_t n0, n1, s0, s1;
    tf2x32(k0, k1, 0u, 0u, n0, n1);
    tf2x32(k0, k1, 0u, 1u, s0, s1);
    ka.k[2 * t] = s0; ka.k[2 * t + 1] = s1;
    k0 = n0; k1 = n1;
  }
  return ka;
}

// 32-bit draw i (of 65536) for this step's subkey: w0^w1 of E_sub(0, i)
__device__ inline uint32_t gumbel_bits(uint32_t sk0, uint32_t sk1, int i) {
  uint32_t o0, o1;
  tf2x32(sk0, sk1, 0u, (uint32_t)i, o0, o1);
  return o0 ^ o1;
}

// fast tanh for the score hot loop; abs err ~2e-7 (clamp avoids inf/inf NaN)
__device__ inline float fast_tanh(float x) {
  float cx = fminf(9.0f, fmaxf(-9.0f, x));
  float t = __expf(2.0f * cx);
  return (t - 1.0f) * __builtin_amdgcn_rcpf(t + 1.0f);
}

// ---- setup kernel 1: transpose weights for coalesced access (R4 layout) ---
__global__ void k_transpose(const float* __restrict__ Wih, const float* __restrict__ Whh,
                            const float* __restrict__ W2, const float* __restrict__ W1,
                            float* __restrict__ WihT, float* __restrict__ WhhT,
                            float* __restrict__ W2T, float* __restrict__ W1T) {
  int i = blockIdx.x * blockDim.x + threadIdx.x;
  if (i < H * G4) {
    int h = i >> 9, j = i & (G4 - 1);
    WihT[i] = Wih[j * H + h];
  } else if (i < 2 * H * G4) {
    int q = i - H * G4; int h = q >> 9, j = q & (G4 - 1);
    WhhT[q] = Whh[j * H + h];
  } else if (i < 2 * H * G4 + H * H) {
    int q = i - 2 * H * G4; int h = q >> 7, k = q & (H - 1);
    W2T[q] = W2[k * H + h];
  } else if (i < 2 * H * G4 + 2 * H * H) {
    int q = i - 2 * H * G4 - H * H; int h = q >> 7, k = q & (H - 1);
    W1T[q] = W1[k * H + h];
  }
}

// ---- setup kernel 2: encT2[b,k,n] = sum_h enc[b,n,h] * W1[k,h] ------------
// (k-major output for the decode score SGEMV). 16 enc rows staged in LDS;
// 256 threads = 128 k x 2 n-groups; per-thread 8 consecutive n -> 2x float4.
__global__ __launch_bounds__(256) void k_enc_trans(const float* __restrict__ enc,
                                                   const float* __restrict__ W1T,
                                                   float* __restrict__ encT2) {
  __shared__ __align__(16) float es[16 * 128];  // 8 KB
  int blk = blockIdx.x;
  int b = blk >> 5;               // 32 blocks per batch
  int n0 = (blk & 31) << 4;       // 16 rows
  const float* src = enc + ((size_t)b * N + n0) * H;
  for (int i = threadIdx.x; i < 16 * 128; i += 256) es[i] = src[i];
  __syncthreads();
  int k = threadIdx.x & 127, ng = threadIdx.x >> 7;
  float acc[8] = {0.f, 0.f, 0.f, 0.f, 0.f, 0.f, 0.f, 0.f};
  for (int h = 0; h < H; h += 4) {
    float w0 = W1T[(h + 0) * H + k];   // coalesced (lanes = consecutive k)
    float w1 = W1T[(h + 1) * H + k];
    float w2 = W1T[(h + 2) * H + k];
    float w3 = W1T[(h + 3) * H + k];
#pragma unroll
    for (int j = 0; j < 8; ++j) {
      const float4 e = *(const float4*)&es[(ng * 8 + j) * 128 + h];  // broadcast
      acc[j] += w0 * e.x + w1 * e.y + w2 * e.z + w3 * e.w;
    }
  }
  float* dst = encT2 + (size_t)b * H * N + (size_t)k * N + n0 + ng * 8;
  ((float4*)dst)[0] = make_float4(acc[0], acc[1], acc[2], acc[3]);
  ((float4*)dst)[1] = make_float4(acc[4], acc[5], acc[6], acc[7]);
}

#define REP16(M) M(0) M(1) M(2) M(3) M(4) M(5) M(6) M(7) \
                 M(8) M(9) M(10) M(11) M(12) M(13) M(14) M(15)

// ---- main fused decoder: 1 batch/block, 512 threads (8 waves) -------------
// Dynamic LDS (128 KB): e_lds[64][512] = encT2[b][64..127][:] (k-half 1).
// k-half 0 lives in 16 named float4 registers per thread (thread = node n).
__global__ __launch_bounds__(512)
__attribute__((amdgpu_waves_per_eu(2, 2))) void k_decode(
    const float* __restrict__ enc, const float* __restrict__ encT2,
    const float* __restrict__ WihT, const float* __restrict__ WhhT,
    const float* __restrict__ W2T,
    const float* __restrict__ bih, const float* __restrict__ bhh,
    const float* __restrict__ v,
    KeyArgs keys, float* __restrict__ out) {
  __shared__ __align__(16) float xs[H];     // dec_input
  __shared__ __align__(16) float hs[H];     // hx
  __shared__ __align__(16) float cs[H];     // cx
  __shared__ __align__(16) float dt[H];     // dec_trans = hx @ W2^T
  __shared__ __align__(16) float vv[H];
  __shared__ __align__(16) float bsum[G4];  // b_ih + b_hh
  __shared__ float pg[G4];                  // gate pre-activations (sans bias)
  __shared__ float pdt[4][H];               // dt partials (and init-mean)
  __shared__ float sc[N];                   // masked scores
  __shared__ float wr_z[8], wr_m[8], wr_s[8];
  __shared__ int wr_i[8];

  extern __shared__ __align__(16) float e_lds[];  // 64*512 floats = 128 KB

  const int tid = threadIdx.x;   // owns node n = tid and gate j = tid
  const int b = blockIdx.x;
  const int lane = tid & 63;
  const int wave = tid >> 6;     // 0..7

  // ---- register-stage encT2[b][0..63][tid]: 16 named float4 (no alloca) ---
  const float* ep = encT2 + (size_t)b * (H * N) + tid;
#define ERLD(i) float4 er##i = make_float4(ep[(size_t)(4*i+0) * N], \
                                           ep[(size_t)(4*i+1) * N], \
                                           ep[(size_t)(4*i+2) * N], \
                                           ep[(size_t)(4*i+3) * N]);
  REP16(ERLD)
#undef ERLD

  // ---- LDS-stage encT2[b][64..127][:] (128 KB), coalesced float4 ----------
  {
    const float4* src4 = (const float4*)(encT2 + (size_t)b * (H * N) + (size_t)64 * N);
    float4* dst4 = (float4*)e_lds;
#pragma unroll
    for (int i = 0; i < 16; ++i) dst4[tid + i * 512] = src4[tid + i * 512];
  }

  // ---- init: dec_input = mean_n enc[b,n,:]; h = c = 0 ----
  {
    int h = tid & 127, part = tid >> 7;
    float s = 0.f;
    const float* p = enc + ((size_t)b * N + part * 128) * H + h;
#pragma unroll 8
    for (int n = 0; n < 128; ++n) s += p[(size_t)n * H];  // coalesced across h
    pdt[part][h] = s;
    bsum[tid] = bih[tid] + bhh[tid];
  }
  if (tid < 128) { hs[tid] = 0.f; cs[tid] = 0.f; vv[tid] = v[tid]; }
  __syncthreads();
  if (tid < 128)
    xs[tid] = (pdt[0][tid] + pdt[1][tid] + pdt[2][tid] + pdt[3][tid]) * (1.0f / N);
  bool masked = false;     // thread tid owns node tid
  int sidx_r = 0;          // previous step's sampled idx (uniform across thr)
  float smax_r = 0.f;      // previous step's score max
  __syncthreads();

  for (int t = 0; t < T; ++t) {
    // === S1: gates (R4's P1 VERBATIM -- scalar wi/wh loads, do not touch).
    // Thread 0 also emits the previous step's outputs under the GEMV. ======
    {
      if (tid == 0 && t > 0) {
        float sum = wr_s[0] + wr_s[1] + wr_s[2] + wr_s[3]
                  + wr_s[4] + wr_s[5] + wr_s[6] + wr_s[7];
        float p = expf(sc[sidx_r] - smax_r) / sum;
        out[(size_t)b * T + (t - 1)] = (float)sidx_r;
        out[(size_t)B * T + (size_t)b * T + (t - 1)] = logf(p + 1e-9f);
      }
      const float* wi = WihT + tid;
      const float* wh = WhhT + tid;
      float a0x = 0.f, a0h = 0.f, a1x = 0.f, a1h = 0.f;
#pragma unroll 8
      for (int h = 0; h < 64; h += 4) {
        const float4 xv = *(const float4*)&xs[h];
        a0x += wi[(size_t)(h + 0) * G4] * xv.x;
        a0x += wi[(size_t)(h + 1) * G4] * xv.y;
        a0x += wi[(size_t)(h + 2) * G4] * xv.z;
        a0x += wi[(size_t)(h + 3) * G4] * xv.w;
        const float4 hv = *(const float4*)&hs[h];
        a0h += wh[(size_t)(h + 0) * G4] * hv.x;
        a0h += wh[(size_t)(h + 1) * G4] * hv.y;
        a0h += wh[(size_t)(h + 2) * G4] * hv.z;
        a0h += wh[(size_t)(h + 3) * G4] * hv.w;
      }
#pragma unroll 8
      for (int h = 64; h < 128; h += 4) {
        const float4 xv = *(const float4*)&xs[h];
        a1x += wi[(size_t)(h + 0) * G4] * xv.x;
        a1x += wi[(size_t)(h + 1) * G4] * xv.y;
        a1x += wi[(size_t)(h + 2) * G4] * xv.z;
        a1x += wi[(size_t)(h + 3) * G4] * xv.w;
        const float4 hv = *(const float4*)&hs[h];
        a1h += wh[(size_t)(h + 0) * G4] * hv.x;
        a1h += wh[(size_t)(h + 1) * G4] * hv.y;
        a1h += wh[(size_t)(h + 2) * G4] * hv.z;
        a1h += wh[(size_t)(h + 3) * G4] * hv.w;
      }
      pg[tid] = (a0x + a0h) + (a1x + a1h);
    }
    __syncthreads();
    // === S2: cell update (torch gate order i,f,g,o) -- R4 verbatim ========
    if (tid < 128) {
      float gi = pg[tid] + bsum[tid];
      float gf = pg[H + tid] + bsum[H + tid];
      float gg = pg[2 * H + tid] + bsum[2 * H + tid];
      float go = pg[3 * H + tid] + bsum[3 * H + tid];
      gi = 1.0f / (1.0f + expf(-gi));
      gf = 1.0f / (1.0f + expf(-gf));
      gg = tanhf(gg);
      go = 1.0f / (1.0f + expf(-go));
      float c = gf * cs[tid] + gi * gg;
      cs[tid] = c;
      hs[tid] = go * tanhf(c);
    }
    __syncthreads();
    // === S3: dt partials (R4's P3 VERBATIM -- scalar w2 loads) ============
    {
      int k = tid & 127, part = tid >> 7;
      const float* w2 = W2T + (size_t)(part * 32) * H + k;
      const int hbp = part * 32;
      float a = 0.f;
#pragma unroll 8
      for (int h = 0; h < 32; h += 4) {
        const float4 hv = *(const float4*)&hs[hbp + h];
        a += w2[(size_t)(h + 0) * H] * hv.x;
        a += w2[(size_t)(h + 1) * H] * hv.y;
        a += w2[(size_t)(h + 2) * H] * hv.z;
        a += w2[(size_t)(h + 3) * H] * hv.w;
      }
      pdt[part][k] = a;
    }
    __syncthreads();
    if (tid < 128) dt[tid] = pdt[0][tid] + pdt[1][tid] + pdt[2][tid] + pdt[3][tid];
    __syncthreads();
    // === S4: scores + gumbel + per-wave argmax (R4's P4+P5a verbatim) =====
    float s;
    {
      float a0 = 0.f, a1 = 0.f;
#define P4A(i) { const float4 dv = *(const float4*)&dt[4 * i];              \
                 const float4 vw = *(const float4*)&vv[4 * i];              \
                 a0 += vw.x * fast_tanh(er##i.x + dv.x);                    \
                 a1 += vw.y * fast_tanh(er##i.y + dv.y);                    \
                 a0 += vw.z * fast_tanh(er##i.z + dv.z);                    \
                 a1 += vw.w * fast_tanh(er##i.w + dv.w); }
      REP16(P4A)
#undef P4A
      float b0 = 0.f, b1 = 0.f;
#pragma unroll
      for (int k4 = 0; k4 < 64; k4 += 4) {
        const float e0 = e_lds[(k4 + 0) * N + tid];
        const float e1 = e_lds[(k4 + 1) * N + tid];
        const float e2 = e_lds[(k4 + 2) * N + tid];
        const float e3 = e_lds[(k4 + 3) * N + tid];
        const float4 dv = *(const float4*)&dt[64 + k4];
        const float4 vw = *(const float4*)&vv[64 + k4];
        b0 += vw.x * fast_tanh(e0 + dv.x);
        b1 += vw.y * fast_tanh(e1 + dv.y);
        b0 += vw.z * fast_tanh(e2 + dv.z);
        b1 += vw.w * fast_tanh(e3 + dv.w);
      }
      const float s_score = (a0 + a1) + (b0 + b1);
      s = masked ? -INFINITY : s_score;
      sc[tid] = s;
      uint32_t bits = gumbel_bits(keys.k[2 * t], keys.k[2 * t + 1], b * N + tid);
      // XLA uniform(minval=tiny, maxval=1): bits->[1,2)->-1, +tiny, max
      float f = __uint_as_float((bits >> 9) | 0x3f800000u) - 1.0f;
      float u = fmaxf(TINYF, f + TINYF);
      float g = -logf(-logf(u));  // accurate logf (hw log2 too sloppy near u~1)
      float z = s + g;
      int zi = tid;
      float m = s;
#pragma unroll
      for (int d = 32; d >= 1; d >>= 1) {
        float oz = __shfl_xor(z, d);
        int oi = __shfl_xor(zi, d);
        float om = __shfl_xor(m, d);
        if (oz > z || (oz == z && oi < zi)) { z = oz; zi = oi; }  // first-idx ties
        m = fmaxf(m, om);
      }
      if (lane == 0) { wr_z[wave] = z; wr_i[wave] = zi; wr_m[wave] = m; }
    }
    __syncthreads();
    // === S5: replicated finale (== R4's P5b chain, same bits in every
    //         thread) + softmax partials + mask + next dec_input ===========
    {
      float bz = wr_z[0]; int bi = wr_i[0]; float bm = wr_m[0];
#pragma unroll
      for (int w = 1; w < 8; ++w) {
        if (wr_z[w] > bz || (wr_z[w] == bz && wr_i[w] < bi)) { bz = wr_z[w]; bi = wr_i[w]; }
        bm = fmaxf(bm, wr_m[w]);
      }
      sidx_r = bi; smax_r = bm;
      float xnew = 0.f;
      if (tid < 128) xnew = enc[((size_t)b * N + bi) * H + tid];  // issue early
      float e = expf(s - bm);  // masked: exp(-inf) = 0
#pragma unroll
      for (int d = 32; d >= 1; d >>= 1) e += __shfl_xor(e, d);
      if (lane == 0) wr_s[wave] = e;
      if (tid == bi) masked = true;
      if (tid < 128) xs[tid] = xnew;
    }
    __syncthreads();
  }
  // epilogue: outputs for the final step
  if (tid == 0) {
    float sum = wr_s[0] + wr_s[1] + wr_s[2] + wr_s[3]
              + wr_s[4] + wr_s[5] + wr_s[6] + wr_s[7];
    float p = expf(sc[sidx_r] - smax_r) / sum;
    out[(size_t)b * T + (T - 1)] = (float)sidx_r;
    out[(size_t)B * T + (size_t)b * T + (T - 1)] = logf(p + 1e-9f);
  }
}

// ---------------------------------------------------------------------------
extern "C" void kernel_launch(void* const* d_in, const int* in_sizes, int n_in,
                              void* d_out, int out_size, void* d_ws, size_t ws_size,
                              hipStream_t stream) {
  (void)in_sizes; (void)n_in; (void)out_size; (void)ws_size;
  const float* enc = (const float*)d_in[0];
  const float* Wih = (const float*)d_in[1];
  const float* Whh = (const float*)d_in[2];
  const float* bih = (const float*)d_in[3];
  const float* bhh = (const float*)d_in[4];
  const float* W1  = (const float*)d_in[5];
  const float* W2  = (const float*)d_in[6];
  const float* v   = (const float*)d_in[7];
  float* out = (float*)d_out;
  float* ws = (float*)d_ws;

  // ws layout (floats): WihT 65536 | WhhT 65536 | W2T 16384 | W1T 16384 | encT2 8388608
  float* WihT  = ws;
  float* WhhT  = ws + 65536;
  float* W2T   = ws + 131072;
  float* W1T   = ws + 147456;
  float* encT2 = ws + 163840;   // [b][k][n], ~33.5 MB

  KeyArgs keys = make_subkeys();  // pure host arithmetic: capture-safe

  // allow 128KB dynamic LDS for k_decode (host-side attr; capture-safe)
  static bool lds_attr_set = false;
  if (!lds_attr_set) {
    (void)hipFuncSetAttribute(reinterpret_cast<const void*>(k_decode),
                              hipFuncAttributeMaxDynamicSharedMemorySize, 131072);
    lds_attr_set = true;
  }

  k_transpose<<<640, 256, 0, stream>>>(Wih, Whh, W2, W1, WihT, WhhT, W2T, W1T);
  k_enc_trans<<<B * N / 16, 256, 0, stream>>>(enc, W1T, encT2);
  k_decode<<<B, 512, 131072, stream>>>(enc, encT2, WihT, WhhT, W2T,
                                       bih, bhh, v, keys, out);
}

// Round 11
// 574.493 us; speedup vs baseline: 5.0179x; 1.0104x over previous
//
#include <hip/hip_runtime.h>
#include <cstdint>
#include <cstddef>

// ---------------------------------------------------------------------------
// Pointer-network decoder: B=128 batches decode T=32 steps over N=512 nodes.
// Round 13 = R10's k_decode BYTE-FOR-BYTE (475us, FETCH 35MB, spill-free;
// R6-R9 proved every deeper k_decode restructure regresses >=3x) + a retiled
// k_enc_trans. The setup GEMM was ~70-85us (~15-20% of fp32 peak): 1 k per
// thread meant one LDS b128 enc-read per output per 4-h iter (4.3 GB LDS
// traffic, ~55us at chip LDS BW) and 256MB of W1T L2 re-streaming. New
// tiling: 1024 blocks x 256 thr, block = 64 n-rows (32KB LDS), thread =
// 4k x 8n (32 outputs): enc LDS reads amortized over 4 k (traffic /4) and
// W1 float4-packed (W1P[h4][k], 64MB L2). Each output's h-chain keeps the
// IDENTICAL source expression in identical ascending-h order ->
// same FMA contraction -> encT2 bit-identical -> absmax 0.0 (the guard;
// if nonzero, revert to R10).
// k_decode: 512 thr, waves_per_eu(2,2), er regs + 128KB dyn LDS, 6 barriers.
// ---------------------------------------------------------------------------

constexpr int B = 128, N = 512, H = 128, T = 32;
constexpr int G4 = 4 * H;  // 512
constexpr float TINYF = 1.17549435e-38f;  // np.finfo(float32).tiny

// ---- JAX threefry2x32 block cipher (20 rounds) ----------------------------
__host__ __device__ inline uint32_t rotl32(uint32_t v, int d) {
  return (v << d) | (v >> (32 - d));
}

__host__ __device__ inline void tf2x32(uint32_t k0, uint32_t k1,
                                       uint32_t x0, uint32_t x1,
                                       uint32_t& o0, uint32_t& o1) {
  uint32_t ks2 = k0 ^ k1 ^ 0x1BD11BDAu;
  x0 += k0; x1 += k1;
#define TF_R(r) x0 += x1; x1 = rotl32(x1, (r)); x1 ^= x0;
  TF_R(13) TF_R(15) TF_R(26) TF_R(6)
  x0 += k1; x1 += ks2 + 1u;
  TF_R(17) TF_R(29) TF_R(16) TF_R(24)
  x0 += ks2; x1 += k0 + 2u;
  TF_R(13) TF_R(15) TF_R(26) TF_R(6)
  x0 += k0; x1 += k1 + 3u;
  TF_R(17) TF_R(29) TF_R(16) TF_R(24)
  x0 += k1; x1 += ks2 + 4u;
  TF_R(13) TF_R(15) TF_R(26) TF_R(6)
  x0 += ks2; x1 += k0 + 5u;
#undef TF_R
  o0 = x0; o1 = x1;
}

struct KeyArgs { uint32_t k[2 * T]; };  // per-step subkeys, 256 B by value

// Host-side key chain (partitionable split): key0 = (0,42);
// new_key = E_key(0,0), sub = E_key(0,1).
static KeyArgs make_subkeys() {
  KeyArgs ka;
  uint32_t k0 = 0u, k1 = 42u;
  for (int t = 0; t < T; ++t) {
    uint32_t n0, n1, s0, s1;
    tf2x32(k0, k1, 0u, 0u, n0, n1);
    tf2x32(k0, k1, 0u, 1u, s0, s1);
    ka.k[2 * t] = s0; ka.k[2 * t + 1] = s1;
    k0 = n0; k1 = n1;
  }
  return ka;
}

// 32-bit draw i (of 65536) for this step's subkey: w0^w1 of E_sub(0, i)
__device__ inline uint32_t gumbel_bits(uint32_t sk0, uint32_t sk1, int i) {
  uint32_t o0, o1;
  tf2x32(sk0, sk1, 0u, (uint32_t)i, o0, o1);
  return o0 ^ o1;
}

// fast tanh for the score hot loop; abs err ~2e-7 (clamp avoids inf/inf NaN)
__device__ inline float fast_tanh(float x) {
  float cx = fminf(9.0f, fmaxf(-9.0f, x));
  float t = __expf(2.0f * cx);
  return (t - 1.0f) * __builtin_amdgcn_rcpf(t + 1.0f);
}

// ---- setup kernel 1: transpose weights for coalesced access ---------------
// WihT/WhhT/W2T: R4/R10 layouts (scalar-load streams in k_decode -- R9
// proved packing THOSE breaks L2 residency; do not touch).
// 4th slot now holds W1P: float4-packed W1P[(h4*128 + k)*4 + c] = W1[k][4*h4+c]
// (only consumed by k_enc_trans).
__global__ void k_transpose(const float* __restrict__ Wih, const float* __restrict__ Whh,
                            const float* __restrict__ W2, const float* __restrict__ W1,
                            float* __restrict__ WihT, float* __restrict__ WhhT,
                            float* __restrict__ W2T, float* __restrict__ W1P) {
  int i = blockIdx.x * blockDim.x + threadIdx.x;
  if (i < H * G4) {
    int h = i >> 9, j = i & (G4 - 1);
    WihT[i] = Wih[j * H + h];
  } else if (i < 2 * H * G4) {
    int q = i - H * G4; int h = q >> 9, j = q & (G4 - 1);
    WhhT[q] = Whh[j * H + h];
  } else if (i < 2 * H * G4 + H * H) {
    int q = i - 2 * H * G4; int h = q >> 7, k = q & (H - 1);
    W2T[q] = W2[k * H + h];
  } else if (i < 2 * H * G4 + 2 * H * H) {
    int q = i - 2 * H * G4 - H * H;
    int c = q & 3, k = (q >> 2) & 127, h4 = q >> 9;
    W1P[q] = W1[k * H + h4 * 4 + c];
  }
}

// ---- setup kernel 2 (RETILED): encT2[b,k,n] = sum_h enc[b,n,h]*W1[k,h] ----
// 1024 blocks (128 b x 8 chunks of 64 n-rows) x 256 threads.
// Thread = 4k x 8n tile (kq = tid&31 -> k = kq*4+i; ng = tid>>5 -> n =
// ng*8+j). Per h4-iter: 4x b128 W1P global (L2-hot, 64KB total) + 8x b128
// enc LDS (2-address broadcast per wave -> conflict-free).
// Per-output h-chain: ascending h4, acc += w0*ex + w1*ey + w2*ez + w3*ew
// with w0..w3 = W1[k][h..h+3] -- the EXACT expression/order of the old
// kernel -> encT2 bit-identical.
__global__ __launch_bounds__(256) void k_enc_trans(const float* __restrict__ enc,
                                                   const float* __restrict__ W1P,
                                                   float* __restrict__ encT2) {
  __shared__ __align__(16) float es[64 * 128];  // 32 KB
  const int blk = blockIdx.x;
  const int b = blk >> 3;              // 8 blocks per batch
  const int n0 = (blk & 7) << 6;       // 64 rows per block
  const int tid = threadIdx.x;

  // stage enc[b][n0..n0+63][:], coalesced float4
  {
    const float4* src4 = (const float4*)(enc + ((size_t)b * N + n0) * H);
    float4* dst4 = (float4*)es;
#pragma unroll
    for (int i = 0; i < 8; ++i) dst4[tid + i * 256] = src4[tid + i * 256];
  }
  __syncthreads();

  const int kq = tid & 31;             // k-quad: k = kq*4 .. kq*4+3
  const int ng = tid >> 5;             // n-group: n = ng*8 .. ng*8+7
  const float4* w4 = (const float4*)W1P + kq * 4;     // + h4*128 per iter
  const float4* es4 = (const float4*)es + ng * 8 * 32;  // rows ng*8.., 32 f4/row

  float acc[4][8];
#pragma unroll
  for (int i = 0; i < 4; ++i)
#pragma unroll
    for (int j = 0; j < 8; ++j) acc[i][j] = 0.f;

  for (int h4 = 0; h4 < 32; ++h4) {
    float4 wp[4];
#pragma unroll
    for (int i = 0; i < 4; ++i) wp[i] = w4[h4 * 128 + i];
    float4 e[8];
#pragma unroll
    for (int j = 0; j < 8; ++j) e[j] = es4[j * 32 + h4];
#pragma unroll
    for (int i = 0; i < 4; ++i)
#pragma unroll
      for (int j = 0; j < 8; ++j)
        acc[i][j] += wp[i].x * e[j].x + wp[i].y * e[j].y +
                     wp[i].z * e[j].z + wp[i].w * e[j].w;
  }

#pragma unroll
  for (int i = 0; i < 4; ++i) {
    float* dst = encT2 + (size_t)b * (H * N) + (size_t)(kq * 4 + i) * N + n0 + ng * 8;
    ((float4*)dst)[0] = make_float4(acc[i][0], acc[i][1], acc[i][2], acc[i][3]);
    ((float4*)dst)[1] = make_float4(acc[i][4], acc[i][5], acc[i][6], acc[i][7]);
  }
}

#define REP16(M) M(0) M(1) M(2) M(3) M(4) M(5) M(6) M(7) \
                 M(8) M(9) M(10) M(11) M(12) M(13) M(14) M(15)

// ---- main fused decoder: 1 batch/block, 512 threads (8 waves) -------------
// R10 VERBATIM. Dynamic LDS (128 KB): e_lds[64][512] = encT2[b][64..127][:];
// k 0..63 in 16 named float4 regs. 6 barriers/step, replicated S5 finale.
__global__ __launch_bounds__(512)
__attribute__((amdgpu_waves_per_eu(2, 2))) void k_decode(
    const float* __restrict__ enc, const float* __restrict__ encT2,
    const float* __restrict__ WihT, const float* __restrict__ WhhT,
    const float* __restrict__ W2T,
    const float* __restrict__ bih, const float* __restrict__ bhh,
    const float* __restrict__ v,
    KeyArgs keys, float* __restrict__ out) {
  __shared__ __align__(16) float xs[H];     // dec_input
  __shared__ __align__(16) float hs[H];     // hx
  __shared__ __align__(16) float cs[H];     // cx
  __shared__ __align__(16) float dt[H];     // dec_trans = hx @ W2^T
  __shared__ __align__(16) float vv[H];
  __shared__ __align__(16) float bsum[G4];  // b_ih + b_hh
  __shared__ float pg[G4];                  // gate pre-activations (sans bias)
  __shared__ float pdt[4][H];               // dt partials (and init-mean)
  __shared__ float sc[N];                   // masked scores
  __shared__ float wr_z[8], wr_m[8], wr_s[8];
  __shared__ int wr_i[8];

  extern __shared__ __align__(16) float e_lds[];  // 64*512 floats = 128 KB

  const int tid = threadIdx.x;   // owns node n = tid and gate j = tid
  const int b = blockIdx.x;
  const int lane = tid & 63;
  const int wave = tid >> 6;     // 0..7

  // ---- register-stage encT2[b][0..63][tid]: 16 named float4 (no alloca) ---
  const float* ep = encT2 + (size_t)b * (H * N) + tid;
#define ERLD(i) float4 er##i = make_float4(ep[(size_t)(4*i+0) * N], \
                                           ep[(size_t)(4*i+1) * N], \
                                           ep[(size_t)(4*i+2) * N], \
                                           ep[(size_t)(4*i+3) * N]);
  REP16(ERLD)
#undef ERLD

  // ---- LDS-stage encT2[b][64..127][:] (128 KB), coalesced float4 ----------
  {
    const float4* src4 = (const float4*)(encT2 + (size_t)b * (H * N) + (size_t)64 * N);
    float4* dst4 = (float4*)e_lds;
#pragma unroll
    for (int i = 0; i < 16; ++i) dst4[tid + i * 512] = src4[tid + i * 512];
  }

  // ---- init: dec_input = mean_n enc[b,n,:]; h = c = 0 ----
  {
    int h = tid & 127, part = tid >> 7;
    float s = 0.f;
    const float* p = enc + ((size_t)b * N + part * 128) * H + h;
#pragma unroll 8
    for (int n = 0; n < 128; ++n) s += p[(size_t)n * H];  // coalesced across h
    pdt[part][h] = s;
    bsum[tid] = bih[tid] + bhh[tid];
  }
  if (tid < 128) { hs[tid] = 0.f; cs[tid] = 0.f; vv[tid] = v[tid]; }
  __syncthreads();
  if (tid < 128)
    xs[tid] = (pdt[0][tid] + pdt[1][tid] + pdt[2][tid] + pdt[3][tid]) * (1.0f / N);
  bool masked = false;     // thread tid owns node tid
  int sidx_r = 0;          // previous step's sampled idx (uniform across thr)
  float smax_r = 0.f;      // previous step's score max
  __syncthreads();

  for (int t = 0; t < T; ++t) {
    // === S1: gates (scalar wi/wh loads -- do not touch). Thread 0 also
    // emits the previous step's outputs under the GEMV. ====================
    {
      if (tid == 0 && t > 0) {
        float sum = wr_s[0] + wr_s[1] + wr_s[2] + wr_s[3]
                  + wr_s[4] + wr_s[5] + wr_s[6] + wr_s[7];
        float p = expf(sc[sidx_r] - smax_r) / sum;
        out[(size_t)b * T + (t - 1)] = (float)sidx_r;
        out[(size_t)B * T + (size_t)b * T + (t - 1)] = logf(p + 1e-9f);
      }
      const float* wi = WihT + tid;
      const float* wh = WhhT + tid;
      float a0x = 0.f, a0h = 0.f, a1x = 0.f, a1h = 0.f;
#pragma unroll 8
      for (int h = 0; h < 64; h += 4) {
        const float4 xv = *(const float4*)&xs[h];
        a0x += wi[(size_t)(h + 0) * G4] * xv.x;
        a0x += wi[(size_t)(h + 1) * G4] * xv.y;
        a0x += wi[(size_t)(h + 2) * G4] * xv.z;
        a0x += wi[(size_t)(h + 3) * G4] * xv.w;
        const float4 hv = *(const float4*)&hs[h];
        a0h += wh[(size_t)(h + 0) * G4] * hv.x;
        a0h += wh[(size_t)(h + 1) * G4] * hv.y;
        a0h += wh[(size_t)(h + 2) * G4] * hv.z;
        a0h += wh[(size_t)(h + 3) * G4] * hv.w;
      }
#pragma unroll 8
      for (int h = 64; h < 128; h += 4) {
        const float4 xv = *(const float4*)&xs[h];
        a1x += wi[(size_t)(h + 0) * G4] * xv.x;
        a1x += wi[(size_t)(h + 1) * G4] * xv.y;
        a1x += wi[(size_t)(h + 2) * G4] * xv.z;
        a1x += wi[(size_t)(h + 3) * G4] * xv.w;
        const float4 hv = *(const float4*)&hs[h];
        a1h += wh[(size_t)(h + 0) * G4] * hv.x;
        a1h += wh[(size_t)(h + 1) * G4] * hv.y;
        a1h += wh[(size_t)(h + 2) * G4] * hv.z;
        a1h += wh[(size_t)(h + 3) * G4] * hv.w;
      }
      pg[tid] = (a0x + a0h) + (a1x + a1h);
    }
    __syncthreads();
    // === S2: cell update (torch gate order i,f,g,o) =======================
    if (tid < 128) {
      float gi = pg[tid] + bsum[tid];
      float gf = pg[H + tid] + bsum[H + tid];
      float gg = pg[2 * H + tid] + bsum[2 * H + tid];
      float go = pg[3 * H + tid] + bsum[3 * H + tid];
      gi = 1.0f / (1.0f + expf(-gi));
      gf = 1.0f / (1.0f + expf(-gf));
      gg = tanhf(gg);
      go = 1.0f / (1.0f + expf(-go));
      float c = gf * cs[tid] + gi * gg;
      cs[tid] = c;
      hs[tid] = go * tanhf(c);
    }
    __syncthreads();
    // === S3: dt partials (scalar w2 loads -- do not touch) ================
    {
      int k = tid & 127, part = tid >> 7;
      const float* w2 = W2T + (size_t)(part * 32) * H + k;
      const int hbp = part * 32;
      float a = 0.f;
#pragma unroll 8
      for (int h = 0; h < 32; h += 4) {
        const float4 hv = *(const float4*)&hs[hbp + h];
        a += w2[(size_t)(h + 0) * H] * hv.x;
        a += w2[(size_t)(h + 1) * H] * hv.y;
        a += w2[(size_t)(h + 2) * H] * hv.z;
        a += w2[(size_t)(h + 3) * H] * hv.w;
      }
      pdt[part][k] = a;
    }
    __syncthreads();
    if (tid < 128) dt[tid] = pdt[0][tid] + pdt[1][tid] + pdt[2][tid] + pdt[3][tid];
    __syncthreads();
    // === S4: scores + gumbel + per-wave argmax ============================
    float s;
    {
      float a0 = 0.f, a1 = 0.f;
#define P4A(i) { const float4 dv = *(const float4*)&dt[4 * i];              \
                 const float4 vw = *(const float4*)&vv[4 * i];              \
                 a0 += vw.x * fast_tanh(er##i.x + dv.x);                    \
                 a1 += vw.y * fast_tanh(er##i.y + dv.y);                    \
                 a0 += vw.z * fast_tanh(er##i.z + dv.z);                    \
                 a1 += vw.w * fast_tanh(er##i.w + dv.w); }
      REP16(P4A)
#undef P4A
      float b0 = 0.f, b1 = 0.f;
#pragma unroll
      for (int k4 = 0; k4 < 64; k4 += 4) {
        const float e0 = e_lds[(k4 + 0) * N + tid];
        const float e1 = e_lds[(k4 + 1) * N + tid];
        const float e2 = e_lds[(k4 + 2) * N + tid];
        const float e3 = e_lds[(k4 + 3) * N + tid];
        const float4 dv = *(const float4*)&dt[64 + k4];
        const float4 vw = *(const float4*)&vv[64 + k4];
        b0 += vw.x * fast_tanh(e0 + dv.x);
        b1 += vw.y * fast_tanh(e1 + dv.y);
        b0 += vw.z * fast_tanh(e2 + dv.z);
        b1 += vw.w * fast_tanh(e3 + dv.w);
      }
      const float s_score = (a0 + a1) + (b0 + b1);
      s = masked ? -INFINITY : s_score;
      sc[tid] = s;
      uint32_t bits = gumbel_bits(keys.k[2 * t], keys.k[2 * t + 1], b * N + tid);
      // XLA uniform(minval=tiny, maxval=1): bits->[1,2)->-1, +tiny, max
      float f = __uint_as_float((bits >> 9) | 0x3f800000u) - 1.0f;
      float u = fmaxf(TINYF, f + TINYF);
      float g = -logf(-logf(u));  // accurate logf (hw log2 too sloppy near u~1)
      float z = s + g;
      int zi = tid;
      float m = s;
#pragma unroll
      for (int d = 32; d >= 1; d >>= 1) {
        float oz = __shfl_xor(z, d);
        int oi = __shfl_xor(zi, d);
        float om = __shfl_xor(m, d);
        if (oz > z || (oz == z && oi < zi)) { z = oz; zi = oi; }  // first-idx ties
        m = fmaxf(m, om);
      }
      if (lane == 0) { wr_z[wave] = z; wr_i[wave] = zi; wr_m[wave] = m; }
    }
    __syncthreads();
    // === S5: replicated finale + softmax partials + mask + next dec_input ==
    {
      float bz = wr_z[0]; int bi = wr_i[0]; float bm = wr_m[0];
#pragma unroll
      for (int w = 1; w < 8; ++w) {
        if (wr_z[w] > bz || (wr_z[w] == bz && wr_i[w] < bi)) { bz = wr_z[w]; bi = wr_i[w]; }
        bm = fmaxf(bm, wr_m[w]);
      }
      sidx_r = bi; smax_r = bm;
      float xnew = 0.f;
      if (tid < 128) xnew = enc[((size_t)b * N + bi) * H + tid];  // issue early
      float e = expf(s - bm);  // masked: exp(-inf) = 0
#pragma unroll
      for (int d = 32; d >= 1; d >>= 1) e += __shfl_xor(e, d);
      if (lane == 0) wr_s[wave] = e;
      if (tid == bi) masked = true;
      if (tid < 128) xs[tid] = xnew;
    }
    __syncthreads();
  }
  // epilogue: outputs for the final step
  if (tid == 0) {
    float sum = wr_s[0] + wr_s[1] + wr_s[2] + wr_s[3]
              + wr_s[4] + wr_s[5] + wr_s[6] + wr_s[7];
    float p = expf(sc[sidx_r] - smax_r) / sum;
    out[(size_t)b * T + (T - 1)] = (float)sidx_r;
    out[(size_t)B * T + (size_t)b * T + (T - 1)] = logf(p + 1e-9f);
  }
}

// ---------------------------------------------------------------------------
extern "C" void kernel_launch(void* const* d_in, const int* in_sizes, int n_in,
                              void* d_out, int out_size, void* d_ws, size_t ws_size,
                              hipStream_t stream) {
  (void)in_sizes; (void)n_in; (void)out_size; (void)ws_size;
  const float* enc = (const float*)d_in[0];
  const float* Wih = (const float*)d_in[1];
  const float* Whh = (const float*)d_in[2];
  const float* bih = (const float*)d_in[3];
  const float* bhh = (const float*)d_in[4];
  const float* W1  = (const float*)d_in[5];
  const float* W2  = (const float*)d_in[6];
  const float* v   = (const float*)d_in[7];
  float* out = (float*)d_out;
  float* ws = (float*)d_ws;

  // ws layout (floats): WihT 65536 | WhhT 65536 | W2T 16384 | W1P 16384 | encT2 8388608
  float* WihT  = ws;
  float* WhhT  = ws + 65536;
  float* W2T   = ws + 131072;
  float* W1P   = ws + 147456;
  float* encT2 = ws + 163840;   // [b][k][n], ~33.5 MB

  KeyArgs keys = make_subkeys();  // pure host arithmetic: capture-safe

  // allow 128KB dynamic LDS for k_decode (host-side attr; capture-safe)
  static bool lds_attr_set = false;
  if (!lds_attr_set) {
    (void)hipFuncSetAttribute(reinterpret_cast<const void*>(k_decode),
                              hipFuncAttributeMaxDynamicSharedMemorySize, 131072);
    lds_attr_set = true;
  }

  k_transpose<<<640, 256, 0, stream>>>(Wih, Whh, W2, W1, WihT, WhhT, W2T, W1P);
  k_enc_trans<<<B * 8, 256, 0, stream>>>(enc, W1P, encT2);
  k_decode<<<B, 512, 131072, stream>>>(enc, encT2, WihT, WhhT, W2T,
                                       bih, bhh, v, keys, out);
}